// Round 1
// baseline (3044.531 us; speedup 1.0000x reference)
//
#include <hip/hip_runtime.h>
#include <math.h>

#define NN 4096
#define NE 65536
#define DIN 128
#define DM 256
#define NH 4
#define DHD 64
#define NL 3

// ---------------- preprocessing kernels ----------------

__global__ void k_count(const int* __restrict__ row, const int* __restrict__ col,
                        int* __restrict__ cnt_r, int* __restrict__ cnt_c) {
    int e = blockIdx.x * blockDim.x + threadIdx.x;
    if (e < NE) {
        atomicAdd(&cnt_r[row[e]], 1);
        atomicAdd(&cnt_c[col[e]], 1);
    }
}

// exclusive scan of 4096 ints -> start[0..4096]
__global__ void k_scan(const int* __restrict__ cnt, int* __restrict__ start) {
    __shared__ int part[256];
    int t = threadIdx.x;
    int s = 0;
    for (int i = 0; i < 16; ++i) s += cnt[t * 16 + i];
    part[t] = s;
    __syncthreads();
    if (t == 0) {
        int acc = 0;
        for (int i = 0; i < 256; ++i) { int v = part[i]; part[i] = acc; acc += v; }
        start[NN] = acc;
    }
    __syncthreads();
    int acc = part[t];
    for (int i = 0; i < 16; ++i) { start[t * 16 + i] = acc; acc += cnt[t * 16 + i]; }
}

__global__ void k_fill(const int* __restrict__ row, const int* __restrict__ col,
                       const int* __restrict__ sr, const int* __restrict__ sc,
                       int* __restrict__ fr, int* __restrict__ fc,
                       int* __restrict__ csr_col, int* __restrict__ csc_row) {
    int e = blockIdx.x * blockDim.x + threadIdx.x;
    if (e < NE) {
        int r = row[e], c = col[e];
        csr_col[sr[r] + atomicAdd(&fr[r], 1)] = c;
        csc_row[sc[c] + atomicAdd(&fc[c], 1)] = r;
    }
}

// insertion-sort each segment (avg len 16) -> deterministic order
__global__ void k_sort(const int* __restrict__ start, int* __restrict__ list) {
    int n = blockIdx.x * blockDim.x + threadIdx.x;
    if (n >= NN) return;
    int a = start[n], b = start[n + 1];
    for (int i = a + 1; i < b; ++i) {
        int v = list[i];
        int j = i - 1;
        while (j >= a && list[j] > v) { list[j + 1] = list[j]; --j; }
        list[j + 1] = v;
    }
}

__global__ void k_dinv(const int* __restrict__ cnt_c, float* __restrict__ dinv) {
    int i = blockIdx.x * blockDim.x + threadIdx.x;
    if (i < NN) dinv[i] = 1.0f / sqrtf((float)(cnt_c[i] + 1));
}

// ---------------- generic tiled f32 GEMM: C = act(alpha*A@B^T + bias) ----------------
// A: M x K (lda), B: Nout x K (ldb), C: M x Nout (ldc). Batched via grid.z strides.
template <int ACT>
__global__ __launch_bounds__(256) void k_gemm(
    const float* __restrict__ A, int lda, long sA,
    const float* __restrict__ B, int ldb, long sB,
    float* __restrict__ C, int ldc, long sC,
    int M, int Nout, int K,
    const float* __restrict__ bias, float alpha) {
    A += (long)blockIdx.z * sA;
    B += (long)blockIdx.z * sB;
    C += (long)blockIdx.z * sC;
    __shared__ float As[16][64];
    __shared__ float Bs[16][64];
    const int tid = threadIdx.x;
    const int tx = tid & 15, ty = tid >> 4;
    const int row0 = blockIdx.y * 64, col0 = blockIdx.x * 64;
    const int lr = tid >> 2;          // 0..63
    const int lk = (tid & 3) * 4;     // 0,4,8,12
    float acc[4][4] = {};
    for (int k0 = 0; k0 < K; k0 += 16) {
        {
            float4 v = *(const float4*)(A + (long)(row0 + lr) * lda + k0 + lk);
            As[lk + 0][lr] = v.x; As[lk + 1][lr] = v.y; As[lk + 2][lr] = v.z; As[lk + 3][lr] = v.w;
        }
        {
            float4 v = *(const float4*)(B + (long)(col0 + lr) * ldb + k0 + lk);
            Bs[lk + 0][lr] = v.x; Bs[lk + 1][lr] = v.y; Bs[lk + 2][lr] = v.z; Bs[lk + 3][lr] = v.w;
        }
        __syncthreads();
#pragma unroll
        for (int kk = 0; kk < 16; ++kk) {
            float a[4], b[4];
#pragma unroll
            for (int i = 0; i < 4; ++i) a[i] = As[kk][ty * 4 + i];
#pragma unroll
            for (int j = 0; j < 4; ++j) b[j] = Bs[kk][tx * 4 + j];
#pragma unroll
            for (int i = 0; i < 4; ++i)
#pragma unroll
                for (int j = 0; j < 4; ++j) acc[i][j] += a[i] * b[j];
        }
        __syncthreads();
    }
#pragma unroll
    for (int i = 0; i < 4; ++i) {
        int r = row0 + ty * 4 + i;
#pragma unroll
        for (int j = 0; j < 4; ++j) {
            int c = col0 + tx * 4 + j;
            float v = acc[i][j] * alpha;
            if (bias) v += bias[c];
            if (ACT == 1) v = fmaxf(v, 0.f);
            C[(long)r * ldc + c] = v;
        }
    }
}

// ---------------- GCN aggregation (CSC gather, deterministic) ----------------
template <int ACT>
__global__ void k_gcn_agg(const float* __restrict__ msg, const int* __restrict__ sc,
                          const int* __restrict__ csc_row, const float* __restrict__ dinv,
                          const float* __restrict__ bias, float* __restrict__ out) {
    int j = blockIdx.x;
    int d = threadIdx.x;  // 0..255
    float acc = 0.f;
    int a = sc[j], b = sc[j + 1];
    for (int i = a; i < b; ++i) {
        int r = csc_row[i];
        acc += dinv[r] * msg[(long)r * DM + d];
    }
    float dj = dinv[j];
    float v = dj * acc + dj * dj * msg[(long)j * DM + d] + bias[d];
    if (ACT) v = fmaxf(v, 0.f);
    out[(long)j * DM + d] = v;
}

__global__ void k_concat(const float* __restrict__ nf, const float* __restrict__ g,
                         float* __restrict__ xc) {
    long i = (long)blockIdx.x * 256 + threadIdx.x;
    if (i >= (long)NN * 384) return;
    int r = (int)(i / 384), c = (int)(i % 384);
    xc[i] = (c < DIN) ? nf[(long)r * DIN + c] : g[(long)r * DM + (c - DIN)];
}

// ---------------- attention pieces ----------------

// add sparse bias into S strip; dedupe consecutive equal cols (set semantics)
__global__ void k_bias_scatter(const int* __restrict__ sr, const int* __restrict__ csr_col,
                               const float* __restrict__ ew, const float* __restrict__ eb,
                               float* __restrict__ S, int m0, int strip) {
    int t = blockIdx.x * blockDim.x + threadIdx.x;
    if (t >= strip) return;
    int row = m0 + t;
    int a = sr[row], b = sr[row + 1];
    float fr = (float)row;
    float w0[NH], w1[NH], w2[NH];
#pragma unroll
    for (int h = 0; h < NH; ++h) {
        w0[h] = ew[h * 3 + 0];
        w1[h] = ew[h * 3 + 1];
        w2[h] = ew[h * 3 + 2] + eb[h];
    }
    int prev = -1;
    for (int i = a; i < b; ++i) {
        int c = csr_col[i];
        if (c == prev) continue;  // duplicate edge: reference .set writes same value once
        prev = c;
        float fc = (float)c;
#pragma unroll
        for (int h = 0; h < NH; ++h) {
            float arg = fr * w0[h] + fc * w1[h] + w2[h];
            float sig = 1.f / (1.f + expf(-arg));
            S[((long)h * strip + t) * NN + c] += sig;
        }
    }
}

__global__ __launch_bounds__(256) void k_softmax(float* __restrict__ S, int strip) {
    int r = blockIdx.x;
    int h = blockIdx.y;
    float* p = S + ((long)h * strip + r) * NN;
    int t = threadIdx.x;
    __shared__ float red[256];
    float mx = -INFINITY;
    for (int i = t; i < NN; i += 256) mx = fmaxf(mx, p[i]);
    red[t] = mx;
    __syncthreads();
    for (int s = 128; s > 0; s >>= 1) { if (t < s) red[t] = fmaxf(red[t], red[t + s]); __syncthreads(); }
    mx = red[0];
    __syncthreads();
    float sum = 0.f;
    for (int i = t; i < NN; i += 256) { float e = expf(p[i] - mx); p[i] = e; sum += e; }
    red[t] = sum;
    __syncthreads();
    for (int s = 128; s > 0; s >>= 1) { if (t < s) red[t] += red[t + s]; __syncthreads(); }
    float inv = 1.f / red[0];
    for (int i = t; i < NN; i += 256) p[i] *= inv;
}

// attnO[m0+m][h*64+d] += sum_k S[(h*strip+m)*NN+k] * V[k][h*64+d]; split-K over grid.y
__global__ __launch_bounds__(256) void k_av(const float* __restrict__ S,
                                            const float* __restrict__ qkv,
                                            float* __restrict__ attnO, int m0, int strip) {
    const int h = blockIdx.z;
    const int bm = blockIdx.x;
    const int kc = blockIdx.y;  // 8 chunks of 512
    __shared__ float As[16][64];
    __shared__ float Bs[16][64];
    const int tid = threadIdx.x;
    const int tx = tid & 15, ty = tid >> 4;
    const int lr = tid >> 2, lk = (tid & 3) * 4;
    float acc[4][4] = {};
    const float* Sh = S + ((long)h * strip + bm * 64) * NN;
    for (int k0 = kc * 512; k0 < kc * 512 + 512; k0 += 16) {
        {
            float4 v = *(const float4*)(Sh + (long)lr * NN + k0 + lk);
            As[lk + 0][lr] = v.x; As[lk + 1][lr] = v.y; As[lk + 2][lr] = v.z; As[lk + 3][lr] = v.w;
        }
        {
            const int kk = tid >> 4, nc = (tid & 15) * 4;
            float4 v = *(const float4*)(qkv + (long)(k0 + kk) * 768 + 512 + h * DHD + nc);
            Bs[kk][nc + 0] = v.x; Bs[kk][nc + 1] = v.y; Bs[kk][nc + 2] = v.z; Bs[kk][nc + 3] = v.w;
        }
        __syncthreads();
#pragma unroll
        for (int kk = 0; kk < 16; ++kk) {
            float a[4], b[4];
#pragma unroll
            for (int i = 0; i < 4; ++i) a[i] = As[kk][ty * 4 + i];
#pragma unroll
            for (int j = 0; j < 4; ++j) b[j] = Bs[kk][tx * 4 + j];
#pragma unroll
            for (int i = 0; i < 4; ++i)
#pragma unroll
                for (int j = 0; j < 4; ++j) acc[i][j] += a[i] * b[j];
        }
        __syncthreads();
    }
#pragma unroll
    for (int i = 0; i < 4; ++i) {
        int gr = m0 + bm * 64 + ty * 4 + i;
#pragma unroll
        for (int j = 0; j < 4; ++j)
            atomicAdd(&attnO[(long)gr * DM + h * DHD + tx * 4 + j], acc[i][j]);
    }
}

// ---------------- layernorm / output ----------------

__global__ void k_add_ln(float* __restrict__ x, const float* __restrict__ y,
                         const float* __restrict__ g, const float* __restrict__ b) {
    int row = blockIdx.x;
    int lane = threadIdx.x;  // 64
    float v[4];
#pragma unroll
    for (int i = 0; i < 4; ++i) v[i] = x[(long)row * DM + lane + 64 * i] + y[(long)row * DM + lane + 64 * i];
    float s = v[0] + v[1] + v[2] + v[3];
#pragma unroll
    for (int o = 1; o < 64; o <<= 1) s += __shfl_xor(s, o);
    float m = s * (1.f / 256.f);
    float q = 0.f;
#pragma unroll
    for (int i = 0; i < 4; ++i) { float d = v[i] - m; q += d * d; }
#pragma unroll
    for (int o = 1; o < 64; o <<= 1) q += __shfl_xor(q, o);
    float rs = rsqrtf(q * (1.f / 256.f) + 1e-5f);
#pragma unroll
    for (int i = 0; i < 4; ++i) {
        int c = lane + 64 * i;
        x[(long)row * DM + c] = (v[i] - m) * rs * g[c] + b[c];
    }
}

__global__ void k_out(const float* __restrict__ x, const float* __restrict__ w,
                      const float* __restrict__ b, float* __restrict__ out) {
    int row = blockIdx.x;
    int lane = threadIdx.x;
    float s = 0.f;
#pragma unroll
    for (int i = 0; i < 4; ++i) s += x[(long)row * DM + lane + 64 * i] * w[lane + 64 * i];
#pragma unroll
    for (int o = 1; o < 64; o <<= 1) s += __shfl_xor(s, o);
    if (lane == 0) out[row] = 1.f / (1.f + expf(-(s + b[0])));
}

__global__ void k_sentinel(float* out, int n) {
    int i = blockIdx.x * blockDim.x + threadIdx.x;
    if (i < n) out[i] = 1.0e9f;  // diagnosable "ws too small" marker
}

// ---------------- host ----------------

extern "C" void kernel_launch(void* const* d_in, const int* in_sizes, int n_in,
                              void* d_out, int out_size, void* d_ws, size_t ws_size,
                              hipStream_t stream) {
    const float* nf = (const float*)d_in[0];
    const int* ei = (const int*)d_in[1];
    const int* erow = ei;
    const int* ecol = ei + NE;
    const float* gcn1_w = (const float*)d_in[2];
    const float* gcn1_b = (const float*)d_in[3];
    const float* gcn2_w = (const float*)d_in[4];
    const float* gcn2_b = (const float*)d_in[5];
    const float* edge_w = (const float*)d_in[6];
    const float* edge_b = (const float*)d_in[7];
    const float* proj_w = (const float*)d_in[8];
    const float* proj_b = (const float*)d_in[9];
    const float* wqkv = (const float*)d_in[10];
    const float* bqkv = (const float*)d_in[11];
    const float* wo = (const float*)d_in[12];
    const float* bo = (const float*)d_in[13];
    const float* ffn_w1 = (const float*)d_in[14];
    const float* ffn_b1 = (const float*)d_in[15];
    const float* ffn_w2 = (const float*)d_in[16];
    const float* ffn_b2 = (const float*)d_in[17];
    const float* ln1_g = (const float*)d_in[18];
    const float* ln1_b = (const float*)d_in[19];
    const float* ln2_g = (const float*)d_in[20];
    const float* ln2_b = (const float*)d_in[21];
    const float* out_w = (const float*)d_in[22];
    const float* out_b = (const float*)d_in[23];
    float* out = (float*)d_out;

    char* w = (char*)d_ws;
    size_t off = 0;
    auto alloc = [&](size_t bytes) -> void* {
        void* p = w + off;
        off = (off + bytes + 255) & ~(size_t)255;
        return p;
    };
    float* x = (float*)alloc((size_t)NN * DM * 4);
    float* xc = (float*)alloc((size_t)NN * 384 * 4);
    float* hbuf = (float*)alloc((size_t)NN * DM * 4);
    float* gbuf = (float*)alloc((size_t)NN * DM * 4);
    float* ybuf = (float*)alloc((size_t)NN * DM * 4);  // msg / attn proj / ffn out
    float* qkv = (float*)alloc((size_t)NN * 768 * 4);
    float* attnO = (float*)alloc((size_t)NN * DM * 4);
    float* ffnH = (float*)alloc((size_t)NN * 1024 * 4);
    float* dinv = (float*)alloc((size_t)NN * 4);
    int* cnt_r = (int*)alloc((size_t)NN * 4);
    int* cnt_c = (int*)alloc((size_t)NN * 4);
    int* sr = (int*)alloc((size_t)(NN + 1) * 4);
    int* sc = (int*)alloc((size_t)(NN + 1) * 4);
    int* fr = (int*)alloc((size_t)NN * 4);
    int* fc = (int*)alloc((size_t)NN * 4);
    int* csr_col = (int*)alloc((size_t)NE * 4);
    int* csc_row = (int*)alloc((size_t)NE * 4);
    float* S = (float*)(w + off);

    size_t rem = (ws_size > off) ? ws_size - off : 0;
    int strip = 0;
    for (int cand : {1024, 512, 256, 128, 64}) {
        if ((size_t)NH * cand * NN * 4 <= rem) { strip = cand; break; }
    }
    if (strip == 0) {
        k_sentinel<<<(out_size + 255) / 256, 256, 0, stream>>>(out, out_size);
        return;
    }

    // ---- preprocessing: CSR/CSC/deg ----
    hipMemsetAsync(cnt_r, 0, NN * 4, stream);
    hipMemsetAsync(cnt_c, 0, NN * 4, stream);
    hipMemsetAsync(fr, 0, NN * 4, stream);
    hipMemsetAsync(fc, 0, NN * 4, stream);
    k_count<<<NE / 256, 256, 0, stream>>>(erow, ecol, cnt_r, cnt_c);
    k_scan<<<1, 256, 0, stream>>>(cnt_r, sr);
    k_scan<<<1, 256, 0, stream>>>(cnt_c, sc);
    k_fill<<<NE / 256, 256, 0, stream>>>(erow, ecol, sr, sc, fr, fc, csr_col, csc_row);
    k_sort<<<NN / 256, 256, 0, stream>>>(sr, csr_col);
    k_sort<<<NN / 256, 256, 0, stream>>>(sc, csc_row);
    k_dinv<<<NN / 256, 256, 0, stream>>>(cnt_c, dinv);

    // ---- GCN 1: msg = nf @ gcn1_w^T ; h = relu(agg) ----
    k_gemm<0><<<dim3(DM / 64, NN / 64, 1), 256, 0, stream>>>(
        nf, DIN, 0, gcn1_w, DIN, 0, ybuf, DM, 0, NN, DM, DIN, nullptr, 1.f);
    k_gcn_agg<1><<<NN, 256, 0, stream>>>(ybuf, sc, csc_row, dinv, gcn1_b, hbuf);
    // ---- GCN 2 ----
    k_gemm<0><<<dim3(DM / 64, NN / 64, 1), 256, 0, stream>>>(
        hbuf, DM, 0, gcn2_w, DM, 0, ybuf, DM, 0, NN, DM, DM, nullptr, 1.f);
    k_gcn_agg<0><<<NN, 256, 0, stream>>>(ybuf, sc, csc_row, dinv, gcn2_b, gbuf);
    // ---- proj: x = [nf, g] @ proj_w^T + b ----
    k_concat<<<(NN * 384 + 255) / 256, 256, 0, stream>>>(nf, gbuf, xc);
    k_gemm<0><<<dim3(DM / 64, NN / 64, 1), 256, 0, stream>>>(
        xc, 384, 0, proj_w, 384, 0, x, DM, 0, NN, DM, 384, proj_b, 1.f);

    const float scale = 0.125f;  // 1/sqrt(64)
    for (int l = 0; l < NL; ++l) {
        // qkv
        k_gemm<0><<<dim3(768 / 64, NN / 64, 1), 256, 0, stream>>>(
            x, DM, 0, wqkv + (long)l * 768 * DM, DM, 0, qkv, 768, 0, NN, 768, DM,
            bqkv + (long)l * 768, 1.f);
        hipMemsetAsync(attnO, 0, (size_t)NN * DM * 4, stream);
        for (int m0 = 0; m0 < NN; m0 += strip) {
            // S[h][m][n] = scale * Q_h[m0+m] . K_h[n]   (batched over heads via grid.z)
            k_gemm<0><<<dim3(NN / 64, strip / 64, NH), 256, 0, stream>>>(
                qkv + (long)m0 * 768, 768, DHD,
                qkv + 256, 768, DHD,
                S, NN, (long)strip * NN,
                strip, NN, DHD, nullptr, scale);
            k_bias_scatter<<<(strip + 255) / 256, 256, 0, stream>>>(
                sr, csr_col, edge_w, edge_b, S, m0, strip);
            k_softmax<<<dim3(strip, NH), 256, 0, stream>>>(S, strip);
            k_av<<<dim3(strip / 64, 8, NH), 256, 0, stream>>>(S, qkv, attnO, m0, strip);
        }
        // o = attnO @ wo^T + bo ; x = LN(x + o)
        k_gemm<0><<<dim3(DM / 64, NN / 64, 1), 256, 0, stream>>>(
            attnO, DM, 0, wo + (long)l * DM * DM, DM, 0, ybuf, DM, 0, NN, DM, DM,
            bo + (long)l * DM, 1.f);
        k_add_ln<<<NN, 64, 0, stream>>>(x, ybuf, ln1_g + (long)l * DM, ln1_b + (long)l * DM);
        // ffn
        k_gemm<1><<<dim3(1024 / 64, NN / 64, 1), 256, 0, stream>>>(
            x, DM, 0, ffn_w1 + (long)l * 1024 * DM, DM, 0, ffnH, 1024, 0, NN, 1024, DM,
            ffn_b1 + (long)l * 1024, 1.f);
        k_gemm<0><<<dim3(DM / 64, NN / 64, 1), 256, 0, stream>>>(
            ffnH, 1024, 0, ffn_w2 + (long)l * DM * 1024, 1024, 0, ybuf, DM, 0, NN, DM, 1024,
            ffn_b2 + (long)l * DM, 1.f);
        k_add_ln<<<NN, 64, 0, stream>>>(x, ybuf, ln2_g + (long)l * DM, ln2_b + (long)l * DM);
    }
    k_out<<<NN, 64, 0, stream>>>(x, out_w, out_b, out);
}

// Round 2
// 1167.297 us; speedup vs baseline: 2.6082x; 2.6082x over previous
//
#include <hip/hip_runtime.h>
#include <math.h>

#define NN 4096
#define NE 65536
#define DIN 128
#define DM 256
#define NH 4
#define NL 3

typedef __attribute__((ext_vector_type(8))) short bf16x8;
typedef __attribute__((ext_vector_type(4))) float f32x4;

__device__ inline ushort f2b(float f) {
    union { float f; uint u; } v; v.f = f;
    uint r = v.u + 0x7fffu + ((v.u >> 16) & 1u);
    return (ushort)(r >> 16);
}

// ---------------- preprocessing ----------------

__global__ void k_edge1(const int* __restrict__ row, const int* __restrict__ col,
                        uint* __restrict__ bitmap, int* __restrict__ cnt_c,
                        int* __restrict__ bcnt, unsigned char* __restrict__ flag) {
    int e = blockIdx.x * 256 + threadIdx.x;
    if (e >= NE) return;
    int r = row[e], c = col[e];
    atomicAdd(&cnt_c[c], 1);
    uint idx = (uint)r * 4096u + (uint)c;
    uint m = 1u << (idx & 31);
    uint old = atomicOr(&bitmap[idx >> 5], m);
    int isnew = (old & m) ? 0 : 1;
    flag[e] = (unsigned char)isnew;
    if (isnew) atomicAdd(&bcnt[(r >> 6) * 64 + (c >> 6)], 1);
}

__global__ void k_edge2(const int* __restrict__ row, const int* __restrict__ col,
                        const unsigned char* __restrict__ flag,
                        const int* __restrict__ sc, int* __restrict__ fc, int* __restrict__ csc_row,
                        const int* __restrict__ bstart, int* __restrict__ bfill,
                        ushort* __restrict__ ents) {
    int e = blockIdx.x * 256 + threadIdx.x;
    if (e >= NE) return;
    int r = row[e], c = col[e];
    csc_row[sc[c] + atomicAdd(&fc[c], 1)] = r;
    if (flag[e]) {
        int key = (r >> 6) * 64 + (c >> 6);
        ents[bstart[key] + atomicAdd(&bfill[key], 1)] = (ushort)(((r & 63) << 6) | (c & 63));
    }
}

// exclusive scan of 4096 ints -> start[0..4096]
__global__ void k_scan(const int* __restrict__ cnt, int* __restrict__ start) {
    __shared__ int part[256];
    int t = threadIdx.x;
    int s = 0;
    for (int i = 0; i < 16; ++i) s += cnt[t * 16 + i];
    part[t] = s;
    __syncthreads();
    if (t == 0) {
        int acc = 0;
        for (int i = 0; i < 256; ++i) { int v = part[i]; part[i] = acc; acc += v; }
        start[NN] = acc;
    }
    __syncthreads();
    int acc = part[t];
    for (int i = 0; i < 16; ++i) { start[t * 16 + i] = acc; acc += cnt[t * 16 + i]; }
}

__global__ void k_dinv(const int* __restrict__ cnt_c, float* __restrict__ dinv) {
    int i = blockIdx.x * 256 + threadIdx.x;
    if (i < NN) dinv[i] = 1.0f / sqrtf((float)(cnt_c[i] + 1));
}

// ---------------- f32 -> bf16 batch convert ----------------
struct CvtP { const float* s[8]; ushort* d[8]; int n[8]; };
__global__ void k_cvt(CvtP p) {
    int y = blockIdx.y;
    int base = (blockIdx.x * 256 + threadIdx.x) * 4;
    if (base >= p.n[y]) return;
    float4 v = *(const float4*)(p.s[y] + base);
    ushort4 o;
    o.x = f2b(v.x); o.y = f2b(v.y); o.z = f2b(v.z); o.w = f2b(v.w);
    *(ushort4*)(p.d[y] + base) = o;
}

// ---------------- bf16 MFMA GEMM: C = act(A @ B^T + bias) ----------------
// A: M x K bf16 (lda), B: Nout x K bf16 (ldb). 128x128 tile, 4 waves, BK=64.
// FLAGS: 1 = write f32 Cf, 2 = write bf16 Cb, 4 = relu
template <int FLAGS>
__global__ __launch_bounds__(256) void k_gemm_b(
    const ushort* __restrict__ A, int lda,
    const ushort* __restrict__ B, int ldb,
    float* __restrict__ Cf, ushort* __restrict__ Cb, int ldc,
    int K, const float* __restrict__ bias) {
    __shared__ ushort As[128 * 64];
    __shared__ ushort Bs[128 * 64];
    const int tid = threadIdx.x;
    const int w = tid >> 6, l = tid & 63;
    const int l15 = l & 15, l4 = l >> 4;
    const int row0 = blockIdx.y * 128, col0 = blockIdx.x * 128;
    const int wm = (w >> 1) * 64, wn = (w & 1) * 64;
    f32x4 acc[4][4];
#pragma unroll
    for (int i = 0; i < 4; ++i)
#pragma unroll
        for (int j = 0; j < 4; ++j) acc[i][j] = (f32x4){0.f, 0.f, 0.f, 0.f};
    for (int k0 = 0; k0 < K; k0 += 64) {
#pragma unroll
        for (int i = 0; i < 4; ++i) {
            int ci = tid + 256 * i;
            int r = ci >> 3, s = ci & 7;
            bf16x8 va = *(const bf16x8*)(A + (long)(row0 + r) * lda + k0 + s * 8);
            *(bf16x8*)&As[r * 64 + ((s ^ (r & 7)) * 8)] = va;
            bf16x8 vb = *(const bf16x8*)(B + (long)(col0 + r) * ldb + k0 + s * 8);
            *(bf16x8*)&Bs[r * 64 + ((s ^ (r & 7)) * 8)] = vb;
        }
        __syncthreads();
#pragma unroll
        for (int kk = 0; kk < 2; ++kk) {
            bf16x8 af[4], bfr[4];
#pragma unroll
            for (int i = 0; i < 4; ++i) {
                int ar = wm + i * 16 + l15;
                af[i] = *(const bf16x8*)&As[ar * 64 + (((kk * 4 + l4) ^ (ar & 7)) * 8)];
                int br = wn + i * 16 + l15;
                bfr[i] = *(const bf16x8*)&Bs[br * 64 + (((kk * 4 + l4) ^ (br & 7)) * 8)];
            }
#pragma unroll
            for (int i = 0; i < 4; ++i)
#pragma unroll
                for (int j = 0; j < 4; ++j)
                    acc[i][j] = __builtin_amdgcn_mfma_f32_16x16x32_bf16(af[i], bfr[j], acc[i][j], 0, 0, 0);
        }
        __syncthreads();
    }
#pragma unroll
    for (int i = 0; i < 4; ++i)
#pragma unroll
        for (int j = 0; j < 4; ++j) {
            int rb = row0 + wm + i * 16;
            int cb = col0 + wn + j * 16 + l15;
            float bv = bias ? bias[cb] : 0.f;
#pragma unroll
            for (int q = 0; q < 4; ++q) {
                int r = rb + l4 * 4 + q;
                float v = acc[i][j][q] + bv;
                if (FLAGS & 4) v = fmaxf(v, 0.f);
                if (FLAGS & 1) Cf[(long)r * ldc + cb] = v;
                if (FLAGS & 2) Cb[(long)r * ldc + cb] = f2b(v);
            }
        }
}

// ---------------- GCN aggregation ----------------
template <int ACT, int B16>
__global__ void k_gcn_agg(const float* __restrict__ msg, const int* __restrict__ sc,
                          const int* __restrict__ csc_row, const float* __restrict__ dinv,
                          const float* __restrict__ bias,
                          float* __restrict__ outf, ushort* __restrict__ outb) {
    int j = blockIdx.x;
    int d = threadIdx.x;
    float acc = 0.f;
    int a = sc[j], b = sc[j + 1];
    for (int i = a; i < b; ++i) {
        int r = csc_row[i];
        acc += dinv[r] * msg[(long)r * DM + d];
    }
    float dj = dinv[j];
    float v = dj * acc + dj * dj * msg[(long)j * DM + d] + bias[d];
    if (ACT) v = fmaxf(v, 0.f);
    if (B16) outb[(long)j * DM + d] = f2b(v);
    else outf[(long)j * DM + d] = v;
}

__global__ void k_concat(const ushort* __restrict__ nfb, const float* __restrict__ g,
                         ushort* __restrict__ xcb) {
    long i = (long)blockIdx.x * 256 + threadIdx.x;
    if (i >= (long)NN * 384) return;
    int r = (int)(i / 384), c = (int)(i % 384);
    xcb[i] = (c < DIN) ? nfb[(long)r * DIN + c] : f2b(g[(long)r * DM + (c - DIN)]);
}

// ---------------- flash attention with sparse bias ----------------
// grid: (NN/64, NH). 256 threads = 4 waves; wave w owns q-rows w*16..w*16+15.
__global__ __launch_bounds__(256) void k_attn(
    const ushort* __restrict__ qkvb, const float* __restrict__ ew, const float* __restrict__ eb,
    const int* __restrict__ bstart, const ushort* __restrict__ ents,
    ushort* __restrict__ attnOb) {
    __shared__ ushort Kl[64 * 64];   // [c][kslot ^ (c&7)]
    __shared__ ushort VT[64 * 64];   // [d][kslot ^ (d&7)] (transposed V)
    __shared__ ushort Pl[4 * 16 * 64];
    const int qb = blockIdx.x, h = blockIdx.y;
    const int tid = threadIdx.x, w = tid >> 6, l = tid & 63;
    const int l15 = l & 15, l4 = l >> 4;
    const float w0 = ew[h * 3 + 0], w1 = ew[h * 3 + 1], w2 = ew[h * 3 + 2] + eb[h];
    const float scale = 0.125f;
    // Q fragments (A-operand): lane row = l15, k-chunk = l4*8
    bf16x8 qf[2];
    {
        const ushort* qp = qkvb + (long)(qb * 64 + w * 16 + l15) * 768 + h * 64 + l4 * 8;
        qf[0] = *(const bf16x8*)(qp);
        qf[1] = *(const bf16x8*)(qp + 32);
    }
    f32x4 o[4];
#pragma unroll
    for (int f = 0; f < 4; ++f) o[f] = (f32x4){0.f, 0.f, 0.f, 0.f};
    float m_run[4], l_run[4];
#pragma unroll
    for (int j = 0; j < 4; ++j) { m_run[j] = -1e30f; l_run[j] = 0.f; }
    ushort* P = &Pl[w * 1024];

    for (int t = 0; t < NN / 64; ++t) {
        // ---- stage K and V^T ----
        {
            const int kr = tid >> 2;           // tile row 0..63
            const int s0 = (tid & 3) * 2;      // slots s0, s0+1
            const long rbase = (long)(t * 64 + kr) * 768 + h * 64;
            union U8 { bf16x8 v; ushort u[8]; };
            U8 ka, kb2, va, vb2;
            ka.v  = *(const bf16x8*)(qkvb + rbase + 256 + s0 * 8);
            kb2.v = *(const bf16x8*)(qkvb + rbase + 256 + s0 * 8 + 8);
            *(bf16x8*)&Kl[kr * 64 + ((s0 ^ (kr & 7)) * 8)] = ka.v;
            *(bf16x8*)&Kl[kr * 64 + (((s0 + 1) ^ (kr & 7)) * 8)] = kb2.v;
            va.v  = *(const bf16x8*)(qkvb + rbase + 512 + s0 * 8);
            vb2.v = *(const bf16x8*)(qkvb + rbase + 512 + s0 * 8 + 8);
#pragma unroll
            for (int jj = 0; jj < 8; ++jj) {
                int c = s0 * 8 + jj;
                VT[c * 64 + (((kr >> 3) ^ (c & 7)) * 8) + (kr & 7)] = va.u[jj];
                int c2 = c + 8;
                VT[c2 * 64 + (((kr >> 3) ^ (c2 & 7)) * 8) + (kr & 7)] = vb2.u[jj];
            }
        }
        __syncthreads();
        // ---- S = scale * Q K^T ----
        f32x4 s4[4];
#pragma unroll
        for (int f = 0; f < 4; ++f) {
            f32x4 a = (f32x4){0.f, 0.f, 0.f, 0.f};
#pragma unroll
            for (int ks = 0; ks < 2; ++ks) {
                int kc = f * 16 + l15;
                bf16x8 kf = *(const bf16x8*)&Kl[kc * 64 + (((ks * 4 + l4) ^ (kc & 7)) * 8)];
                a = __builtin_amdgcn_mfma_f32_16x16x32_bf16(qf[ks], kf, a, 0, 0, 0);
            }
            s4[f] = a * scale;
        }
        // ---- sparse bias ----
        {
            int bs = bstart[qb * 64 + t], be = bstart[qb * 64 + t + 1];
            for (int i = bs; i < be; ++i) {
                int rc = (int)ents[i];
                int r6 = rc >> 6, c6 = rc & 63;
                if ((r6 >> 4) == w && ((r6 >> 2) & 3) == l4 && (c6 & 15) == l15) {
                    float arg = w0 * (float)(qb * 64 + r6) + w1 * (float)(t * 64 + c6) + w2;
                    float sig = 1.f / (1.f + __expf(-arg));
                    switch (((c6 >> 4) << 2) | (r6 & 3)) {
                        case 0:  s4[0][0] += sig; break; case 1:  s4[0][1] += sig; break;
                        case 2:  s4[0][2] += sig; break; case 3:  s4[0][3] += sig; break;
                        case 4:  s4[1][0] += sig; break; case 5:  s4[1][1] += sig; break;
                        case 6:  s4[1][2] += sig; break; case 7:  s4[1][3] += sig; break;
                        case 8:  s4[2][0] += sig; break; case 9:  s4[2][1] += sig; break;
                        case 10: s4[2][2] += sig; break; case 11: s4[2][3] += sig; break;
                        case 12: s4[3][0] += sig; break; case 13: s4[3][1] += sig; break;
                        case 14: s4[3][2] += sig; break; case 15: s4[3][3] += sig; break;
                    }
                }
            }
        }
        // ---- online softmax ----
        float me[4];
#pragma unroll
        for (int j = 0; j < 4; ++j)
            me[j] = fmaxf(fmaxf(s4[0][j], s4[1][j]), fmaxf(s4[2][j], s4[3][j]));
#pragma unroll
        for (int m = 1; m < 16; m <<= 1)
#pragma unroll
            for (int j = 0; j < 4; ++j) me[j] = fmaxf(me[j], __shfl_xor(me[j], m));
        float fac[4];
#pragma unroll
        for (int j = 0; j < 4; ++j) {
            float mn = fmaxf(m_run[j], me[j]);
            fac[j] = __expf(m_run[j] - mn);
            m_run[j] = mn;
        }
        float rs[4] = {0.f, 0.f, 0.f, 0.f};
#pragma unroll
        for (int f = 0; f < 4; ++f)
#pragma unroll
            for (int j = 0; j < 4; ++j) {
                float p = __expf(s4[f][j] - m_run[j]);
                s4[f][j] = p;
                rs[j] += p;
            }
#pragma unroll
        for (int m = 1; m < 16; m <<= 1)
#pragma unroll
            for (int j = 0; j < 4; ++j) rs[j] += __shfl_xor(rs[j], m);
#pragma unroll
        for (int j = 0; j < 4; ++j) l_run[j] = l_run[j] * fac[j] + rs[j];
#pragma unroll
        for (int f = 0; f < 4; ++f)
#pragma unroll
            for (int j = 0; j < 4; ++j) o[f][j] *= fac[j];
        // ---- P -> per-wave LDS (bf16, swizzled) ----
#pragma unroll
        for (int f = 0; f < 4; ++f)
#pragma unroll
            for (int j = 0; j < 4; ++j) {
                int r16 = l4 * 4 + j, c6 = f * 16 + l15;
                P[r16 * 64 + (((c6 >> 3) ^ (r16 & 7)) * 8) + (c6 & 7)] = f2b(s4[f][j]);
            }
        __builtin_amdgcn_s_waitcnt(0);
        // ---- O += P V ----
#pragma unroll
        for (int ks = 0; ks < 2; ++ks) {
            bf16x8 pa = *(const bf16x8*)&P[l15 * 64 + (((ks * 4 + l4) ^ (l15 & 7)) * 8)];
#pragma unroll
            for (int fd = 0; fd < 4; ++fd) {
                int d = fd * 16 + l15;
                bf16x8 vb = *(const bf16x8*)&VT[d * 64 + (((ks * 4 + l4) ^ (d & 7)) * 8)];
                o[fd] = __builtin_amdgcn_mfma_f32_16x16x32_bf16(pa, vb, o[fd], 0, 0, 0);
            }
        }
        __syncthreads();
    }
    float inv[4];
#pragma unroll
    for (int j = 0; j < 4; ++j) inv[j] = 1.f / l_run[j];
#pragma unroll
    for (int fd = 0; fd < 4; ++fd)
#pragma unroll
        for (int j = 0; j < 4; ++j) {
            int r = qb * 64 + w * 16 + l4 * 4 + j;
            int d = fd * 16 + l15;
            attnOb[(long)r * DM + h * 64 + d] = f2b(o[fd][j] * inv[j]);
        }
}

// ---------------- layernorm / output ----------------

__global__ void k_add_ln(float* __restrict__ x, ushort* __restrict__ xb,
                         const float* __restrict__ y,
                         const float* __restrict__ g, const float* __restrict__ b) {
    int row = blockIdx.x;
    int lane = threadIdx.x;  // 64
    float v[4];
#pragma unroll
    for (int i = 0; i < 4; ++i)
        v[i] = x[(long)row * DM + lane + 64 * i] + y[(long)row * DM + lane + 64 * i];
    float s = v[0] + v[1] + v[2] + v[3];
#pragma unroll
    for (int o = 1; o < 64; o <<= 1) s += __shfl_xor(s, o);
    float m = s * (1.f / 256.f);
    float q = 0.f;
#pragma unroll
    for (int i = 0; i < 4; ++i) { float d = v[i] - m; q += d * d; }
#pragma unroll
    for (int o = 1; o < 64; o <<= 1) q += __shfl_xor(q, o);
    float rs = rsqrtf(q * (1.f / 256.f) + 1e-5f);
#pragma unroll
    for (int i = 0; i < 4; ++i) {
        int c = lane + 64 * i;
        float val = (v[i] - m) * rs * g[c] + b[c];
        x[(long)row * DM + c] = val;
        xb[(long)row * DM + c] = f2b(val);
    }
}

__global__ void k_out(const float* __restrict__ x, const float* __restrict__ w,
                      const float* __restrict__ b, float* __restrict__ out) {
    int row = blockIdx.x;
    int lane = threadIdx.x;
    float s = 0.f;
#pragma unroll
    for (int i = 0; i < 4; ++i) s += x[(long)row * DM + lane + 64 * i] * w[lane + 64 * i];
#pragma unroll
    for (int o = 1; o < 64; o <<= 1) s += __shfl_xor(s, o);
    if (lane == 0) out[row] = 1.f / (1.f + expf(-(s + b[0])));
}

__global__ void k_sentinel(float* out, int n) {
    int i = blockIdx.x * 256 + threadIdx.x;
    if (i < n) out[i] = 1.0e9f;
}

// ---------------- host ----------------

extern "C" void kernel_launch(void* const* d_in, const int* in_sizes, int n_in,
                              void* d_out, int out_size, void* d_ws, size_t ws_size,
                              hipStream_t stream) {
    const float* nf = (const float*)d_in[0];
    const int* ei = (const int*)d_in[1];
    const int* erow = ei;
    const int* ecol = ei + NE;
    const float* gcn1_w = (const float*)d_in[2];
    const float* gcn1_b = (const float*)d_in[3];
    const float* gcn2_w = (const float*)d_in[4];
    const float* gcn2_b = (const float*)d_in[5];
    const float* edge_w = (const float*)d_in[6];
    const float* edge_b = (const float*)d_in[7];
    const float* proj_w = (const float*)d_in[8];
    const float* proj_b = (const float*)d_in[9];
    const float* wqkv = (const float*)d_in[10];
    const float* bqkv = (const float*)d_in[11];
    const float* wo = (const float*)d_in[12];
    const float* bo = (const float*)d_in[13];
    const float* ffn_w1 = (const float*)d_in[14];
    const float* ffn_b1 = (const float*)d_in[15];
    const float* ffn_w2 = (const float*)d_in[16];
    const float* ffn_b2 = (const float*)d_in[17];
    const float* ln1_g = (const float*)d_in[18];
    const float* ln1_b = (const float*)d_in[19];
    const float* ln2_g = (const float*)d_in[20];
    const float* ln2_b = (const float*)d_in[21];
    const float* out_w = (const float*)d_in[22];
    const float* out_b = (const float*)d_in[23];
    float* out = (float*)d_out;

    char* wp = (char*)d_ws;
    size_t off = 0;
    auto alloc = [&](size_t bytes) -> void* {
        void* p = wp + off;
        off = (off + bytes + 255) & ~(size_t)255;
        return p;
    };
    float* x = (float*)alloc((size_t)NN * DM * 4);
    ushort* xb = (ushort*)alloc((size_t)NN * DM * 2);
    ushort* xcb = (ushort*)alloc((size_t)NN * 384 * 2);
    ushort* hb = (ushort*)alloc((size_t)NN * DM * 2);
    float* g = (float*)alloc((size_t)NN * DM * 4);
    float* msg = (float*)alloc((size_t)NN * DM * 4);
    ushort* qkvb = (ushort*)alloc((size_t)NN * 768 * 2);
    ushort* attnOb = (ushort*)alloc((size_t)NN * DM * 2);
    float* ybuf = (float*)alloc((size_t)NN * DM * 4);
    ushort* ffnHb = (ushort*)alloc((size_t)NN * 1024 * 2);
    ushort* nfb = (ushort*)alloc((size_t)NN * DIN * 2);
    ushort* wqkvb = (ushort*)alloc((size_t)NL * 768 * DM * 2);
    ushort* wob = (ushort*)alloc((size_t)NL * DM * DM * 2);
    ushort* f1b = (ushort*)alloc((size_t)NL * 1024 * DM * 2);
    ushort* f2bw = (ushort*)alloc((size_t)NL * DM * 1024 * 2);
    ushort* g1b = (ushort*)alloc((size_t)DM * DIN * 2);
    ushort* g2b = (ushort*)alloc((size_t)DM * DM * 2);
    ushort* pjb = (ushort*)alloc((size_t)DM * 384 * 2);
    uint* bitmap = (uint*)alloc((size_t)NN * NN / 8);
    unsigned char* flag = (unsigned char*)alloc(NE);
    int* cnt_c = (int*)alloc((size_t)NN * 4);
    int* bcnt = (int*)alloc((size_t)NN * 4);
    int* sc = (int*)alloc((size_t)(NN + 1) * 4);
    int* bstart = (int*)alloc((size_t)(NN + 1) * 4);
    int* fc = (int*)alloc((size_t)NN * 4);
    int* bfill = (int*)alloc((size_t)NN * 4);
    int* csc_row = (int*)alloc((size_t)NE * 4);
    ushort* ents = (ushort*)alloc((size_t)NE * 2);
    float* dinv = (float*)alloc((size_t)NN * 4);

    if (off > ws_size) {
        k_sentinel<<<(out_size + 255) / 256, 256, 0, stream>>>(out, out_size);
        return;
    }

    // ---- preprocessing ----
    hipMemsetAsync(bitmap, 0, (size_t)NN * NN / 8, stream);
    hipMemsetAsync(cnt_c, 0, NN * 4, stream);
    hipMemsetAsync(bcnt, 0, NN * 4, stream);
    hipMemsetAsync(fc, 0, NN * 4, stream);
    hipMemsetAsync(bfill, 0, NN * 4, stream);
    k_edge1<<<NE / 256, 256, 0, stream>>>(erow, ecol, bitmap, cnt_c, bcnt, flag);
    k_scan<<<1, 256, 0, stream>>>(cnt_c, sc);
    k_scan<<<1, 256, 0, stream>>>(bcnt, bstart);
    k_edge2<<<NE / 256, 256, 0, stream>>>(erow, ecol, flag, sc, fc, csc_row, bstart, bfill, ents);
    k_dinv<<<NN / 256, 256, 0, stream>>>(cnt_c, dinv);

    // ---- weight/input conversion ----
    CvtP cp;
    cp.s[0] = nf;      cp.d[0] = nfb;   cp.n[0] = NN * DIN;
    cp.s[1] = wqkv;    cp.d[1] = wqkvb; cp.n[1] = NL * 768 * DM;
    cp.s[2] = wo;      cp.d[2] = wob;   cp.n[2] = NL * DM * DM;
    cp.s[3] = ffn_w1;  cp.d[3] = f1b;   cp.n[3] = NL * 1024 * DM;
    cp.s[4] = ffn_w2;  cp.d[4] = f2bw;  cp.n[4] = NL * DM * 1024;
    cp.s[5] = gcn1_w;  cp.d[5] = g1b;   cp.n[5] = DM * DIN;
    cp.s[6] = gcn2_w;  cp.d[6] = g2b;   cp.n[6] = DM * DM;
    cp.s[7] = proj_w;  cp.d[7] = pjb;   cp.n[7] = DM * 384;
    k_cvt<<<dim3(768, 8), 256, 0, stream>>>(cp);

    // ---- GCN ----
    k_gemm_b<1><<<dim3(DM / 128, NN / 128), 256, 0, stream>>>(
        nfb, DIN, g1b, DIN, msg, nullptr, DM, DIN, nullptr);
    k_gcn_agg<1, 1><<<NN, DM, 0, stream>>>(msg, sc, csc_row, dinv, gcn1_b, nullptr, hb);
    k_gemm_b<1><<<dim3(DM / 128, NN / 128), 256, 0, stream>>>(
        hb, DM, g2b, DM, msg, nullptr, DM, DM, nullptr);
    k_gcn_agg<0, 0><<<NN, DM, 0, stream>>>(msg, sc, csc_row, dinv, gcn2_b, g, nullptr);
    // ---- proj ----
    k_concat<<<(NN * 384 + 255) / 256, 256, 0, stream>>>(nfb, g, xcb);
    k_gemm_b<3><<<dim3(DM / 128, NN / 128), 256, 0, stream>>>(
        xcb, 384, pjb, 384, x, xb, DM, 384, proj_b);

    for (int l = 0; l < NL; ++l) {
        k_gemm_b<2><<<dim3(768 / 128, NN / 128), 256, 0, stream>>>(
            xb, DM, wqkvb + (long)l * 768 * DM, DM, nullptr, qkvb, 768, DM,
            bqkv + (long)l * 768);
        k_attn<<<dim3(NN / 64, NH), 256, 0, stream>>>(qkvb, edge_w, edge_b, bstart, ents, attnOb);
        k_gemm_b<1><<<dim3(DM / 128, NN / 128), 256, 0, stream>>>(
            attnOb, DM, wob + (long)l * DM * DM, DM, ybuf, nullptr, DM, DM,
            bo + (long)l * DM);
        k_add_ln<<<NN, 64, 0, stream>>>(x, xb, ybuf, ln1_g + (long)l * DM, ln1_b + (long)l * DM);
        k_gemm_b<6><<<dim3(1024 / 128, NN / 128), 256, 0, stream>>>(
            xb, DM, f1b + (long)l * 1024 * DM, DM, nullptr, ffnHb, 1024, DM,
            ffn_b1 + (long)l * 1024);
        k_gemm_b<1><<<dim3(DM / 128, NN / 128), 256, 0, stream>>>(
            ffnHb, 1024, f2bw + (long)l * DM * 1024, 1024, ybuf, nullptr, DM, 1024,
            ffn_b2 + (long)l * DM);
        k_add_ln<<<NN, 64, 0, stream>>>(x, xb, ybuf, ln2_g + (long)l * DM, ln2_b + (long)l * DM);
    }
    k_out<<<NN, 64, 0, stream>>>(x, out_w, out_b, out);
}

// Round 3
// 817.532 us; speedup vs baseline: 3.7240x; 1.4278x over previous
//
#include <hip/hip_runtime.h>
#include <math.h>

#define NN 4096
#define NE 65536
#define DIN 128
#define DM 256
#define NH 4
#define NL 3
#define NCH 4
#define TPC (NN / 64 / NCH)  // 16 KV tiles per chunk

typedef __attribute__((ext_vector_type(8))) short bf16x8;
typedef __attribute__((ext_vector_type(4))) float f32x4;

__device__ inline ushort f2b(float f) {
    union { float f; uint u; } v; v.f = f;
    uint r = v.u + 0x7fffu + ((v.u >> 16) & 1u);
    return (ushort)(r >> 16);
}

// ---------------- preprocessing ----------------

__global__ void k_edge1(const int* __restrict__ row, const int* __restrict__ col,
                        uint* __restrict__ bitmap, int* __restrict__ cnt_c,
                        int* __restrict__ bcnt, unsigned char* __restrict__ flag) {
    int e = blockIdx.x * 256 + threadIdx.x;
    if (e >= NE) return;
    int r = row[e], c = col[e];
    atomicAdd(&cnt_c[c], 1);
    uint idx = (uint)r * 4096u + (uint)c;
    uint m = 1u << (idx & 31);
    uint old = atomicOr(&bitmap[idx >> 5], m);
    int isnew = (old & m) ? 0 : 1;
    flag[e] = (unsigned char)isnew;
    if (isnew) atomicAdd(&bcnt[(r >> 6) * 64 + (c >> 6)], 1);
}

__global__ void k_edge2(const int* __restrict__ row, const int* __restrict__ col,
                        const unsigned char* __restrict__ flag,
                        const int* __restrict__ sc, int* __restrict__ fc, int* __restrict__ csc_row,
                        const int* __restrict__ bstart, int* __restrict__ bfill,
                        ushort* __restrict__ ents) {
    int e = blockIdx.x * 256 + threadIdx.x;
    if (e >= NE) return;
    int r = row[e], c = col[e];
    csc_row[sc[c] + atomicAdd(&fc[c], 1)] = r;
    if (flag[e]) {
        int key = (r >> 6) * 64 + (c >> 6);
        ents[bstart[key] + atomicAdd(&bfill[key], 1)] = (ushort)(((r & 63) << 6) | (c & 63));
    }
}

// exclusive scan of 4096 ints -> start[0..4096]
__global__ void k_scan(const int* __restrict__ cnt, int* __restrict__ start) {
    __shared__ int part[256];
    int t = threadIdx.x;
    int s = 0;
    for (int i = 0; i < 16; ++i) s += cnt[t * 16 + i];
    part[t] = s;
    __syncthreads();
    if (t == 0) {
        int acc = 0;
        for (int i = 0; i < 256; ++i) { int v = part[i]; part[i] = acc; acc += v; }
        start[NN] = acc;
    }
    __syncthreads();
    int acc = part[t];
    for (int i = 0; i < 16; ++i) { start[t * 16 + i] = acc; acc += cnt[t * 16 + i]; }
}

__global__ void k_dinv(const int* __restrict__ cnt_c, float* __restrict__ dinv) {
    int i = blockIdx.x * 256 + threadIdx.x;
    if (i < NN) dinv[i] = 1.0f / sqrtf((float)(cnt_c[i] + 1));
}

// ---------------- f32 -> bf16 batch convert ----------------
struct CvtP { const float* s[8]; ushort* d[8]; int n[8]; };
__global__ void k_cvt(CvtP p) {
    int y = blockIdx.y;
    int base = (blockIdx.x * 256 + threadIdx.x) * 4;
    if (base >= p.n[y]) return;
    float4 v = *(const float4*)(p.s[y] + base);
    ushort4 o;
    o.x = f2b(v.x); o.y = f2b(v.y); o.z = f2b(v.z); o.w = f2b(v.w);
    *(ushort4*)(p.d[y] + base) = o;
}

// ---------------- bf16 MFMA GEMM: C = act(A @ B^T + bias) ----------------
// FLAGS: 1 = write f32 Cf, 2 = write bf16 Cb, 4 = relu, 8 = write bf16 TRANSPOSED (Cb[c*ldc + r])
template <int FLAGS>
__global__ __launch_bounds__(256) void k_gemm_b(
    const ushort* __restrict__ A, int lda,
    const ushort* __restrict__ B, int ldb,
    float* __restrict__ Cf, ushort* __restrict__ Cb, int ldc,
    int K, const float* __restrict__ bias) {
    __shared__ ushort As[128 * 64];
    __shared__ ushort Bs[128 * 64];
    const int tid = threadIdx.x;
    const int w = tid >> 6, l = tid & 63;
    const int l15 = l & 15, l4 = l >> 4;
    const int row0 = blockIdx.y * 128, col0 = blockIdx.x * 128;
    const int wm = (w >> 1) * 64, wn = (w & 1) * 64;
    f32x4 acc[4][4];
#pragma unroll
    for (int i = 0; i < 4; ++i)
#pragma unroll
        for (int j = 0; j < 4; ++j) acc[i][j] = (f32x4){0.f, 0.f, 0.f, 0.f};
    for (int k0 = 0; k0 < K; k0 += 64) {
#pragma unroll
        for (int i = 0; i < 4; ++i) {
            int ci = tid + 256 * i;
            int r = ci >> 3, s = ci & 7;
            bf16x8 va = *(const bf16x8*)(A + (long)(row0 + r) * lda + k0 + s * 8);
            *(bf16x8*)&As[r * 64 + ((s ^ (r & 7)) * 8)] = va;
            bf16x8 vb = *(const bf16x8*)(B + (long)(col0 + r) * ldb + k0 + s * 8);
            *(bf16x8*)&Bs[r * 64 + ((s ^ (r & 7)) * 8)] = vb;
        }
        __syncthreads();
#pragma unroll
        for (int kk = 0; kk < 2; ++kk) {
            bf16x8 af[4], bfr[4];
#pragma unroll
            for (int i = 0; i < 4; ++i) {
                int ar = wm + i * 16 + l15;
                af[i] = *(const bf16x8*)&As[ar * 64 + (((kk * 4 + l4) ^ (ar & 7)) * 8)];
                int br = wn + i * 16 + l15;
                bfr[i] = *(const bf16x8*)&Bs[br * 64 + (((kk * 4 + l4) ^ (br & 7)) * 8)];
            }
#pragma unroll
            for (int i = 0; i < 4; ++i)
#pragma unroll
                for (int j = 0; j < 4; ++j)
                    acc[i][j] = __builtin_amdgcn_mfma_f32_16x16x32_bf16(af[i], bfr[j], acc[i][j], 0, 0, 0);
        }
        __syncthreads();
    }
#pragma unroll
    for (int i = 0; i < 4; ++i)
#pragma unroll
        for (int j = 0; j < 4; ++j) {
            int rb = row0 + wm + i * 16;
            int cb = col0 + wn + j * 16 + l15;
            float bv = bias ? bias[cb] : 0.f;
            if (FLAGS & 8) {
                ushort4 o4;
                o4.x = f2b(acc[i][j][0] + bv);
                o4.y = f2b(acc[i][j][1] + bv);
                o4.z = f2b(acc[i][j][2] + bv);
                o4.w = f2b(acc[i][j][3] + bv);
                *(ushort4*)(Cb + (long)cb * ldc + rb + l4 * 4) = o4;
            } else {
#pragma unroll
                for (int q = 0; q < 4; ++q) {
                    int r = rb + l4 * 4 + q;
                    float v = acc[i][j][q] + bv;
                    if (FLAGS & 4) v = fmaxf(v, 0.f);
                    if (FLAGS & 1) Cf[(long)r * ldc + cb] = v;
                    if (FLAGS & 2) Cb[(long)r * ldc + cb] = f2b(v);
                }
            }
        }
}

// ---------------- GCN aggregation ----------------
template <int ACT, int B16>
__global__ void k_gcn_agg(const float* __restrict__ msg, const int* __restrict__ sc,
                          const int* __restrict__ csc_row, const float* __restrict__ dinv,
                          const float* __restrict__ bias,
                          float* __restrict__ outf, ushort* __restrict__ outb) {
    int j = blockIdx.x;
    int d = threadIdx.x;
    float acc = 0.f;
    int a = sc[j], b = sc[j + 1];
    for (int i = a; i < b; ++i) {
        int r = csc_row[i];
        acc += dinv[r] * msg[(long)r * DM + d];
    }
    float dj = dinv[j];
    float v = dj * acc + dj * dj * msg[(long)j * DM + d] + bias[d];
    if (ACT) v = fmaxf(v, 0.f);
    if (B16) outb[(long)j * DM + d] = f2b(v);
    else outf[(long)j * DM + d] = v;
}

__global__ void k_concat(const ushort* __restrict__ nfb, const float* __restrict__ g,
                         ushort* __restrict__ xcb) {
    long i = (long)blockIdx.x * 256 + threadIdx.x;
    if (i >= (long)NN * 384) return;
    int r = (int)(i / 384), c = (int)(i % 384);
    xcb[i] = (c < DIN) ? nfb[(long)r * DIN + c] : f2b(g[(long)r * DM + (c - DIN)]);
}

// ---------------- flash attention, KV-split into NCH chunks ----------------
// grid: (NN/64, NH, NCH). 256 threads = 4 waves; wave w owns q-rows w*16..w*16+15.
// Writes unnormalized partial O + (m, l) per row; k_comb merges.
__global__ __launch_bounds__(256) void k_attn(
    const ushort* __restrict__ qkb, const ushort* __restrict__ vT,
    const float* __restrict__ ew, const float* __restrict__ eb,
    const int* __restrict__ bstart, const ushort* __restrict__ ents,
    float* __restrict__ opart, float2* __restrict__ ml) {
    __shared__ ushort Kl[64 * 64];   // [kv-row][kslot swizzled]
    __shared__ ushort Vl[64 * 64];   // [d][kslot swizzled]
    __shared__ ushort Pl[4 * 16 * 64];
    const int qb = blockIdx.x, h = blockIdx.y, cz = blockIdx.z;
    const int tid = threadIdx.x, w = tid >> 6, l = tid & 63;
    const int l15 = l & 15, l4 = l >> 4;
    const float w0 = ew[h * 3 + 0], w1 = ew[h * 3 + 1], w2 = ew[h * 3 + 2] + eb[h];
    const float scale = 0.125f;
    bf16x8 qf[2];
    {
        const ushort* qp = qkb + (long)(qb * 64 + w * 16 + l15) * 512 + h * 64 + l4 * 8;
        qf[0] = *(const bf16x8*)(qp);
        qf[1] = *(const bf16x8*)(qp + 32);
    }
    f32x4 o[4];
#pragma unroll
    for (int f = 0; f < 4; ++f) o[f] = (f32x4){0.f, 0.f, 0.f, 0.f};
    float m_run[4], l_run[4];
#pragma unroll
    for (int j = 0; j < 4; ++j) { m_run[j] = -1e30f; l_run[j] = 0.f; }
    ushort* P = &Pl[w * 1024];

    for (int t = cz * TPC; t < (cz + 1) * TPC; ++t) {
        // ---- stage K rows and V^T rows (both vectorized, swizzled) ----
#pragma unroll
        for (int i = 0; i < 2; ++i) {
            int idx = tid + 256 * i;
            int r = idx >> 3, s = idx & 7;
            bf16x8 kv = *(const bf16x8*)(qkb + (long)(t * 64 + r) * 512 + 256 + h * 64 + s * 8);
            *(bf16x8*)&Kl[r * 64 + ((s ^ (r & 7)) * 8)] = kv;
            bf16x8 vv = *(const bf16x8*)(vT + (long)(h * 64 + r) * NN + t * 64 + s * 8);
            *(bf16x8*)&Vl[r * 64 + ((s ^ (r & 7)) * 8)] = vv;
        }
        __syncthreads();
        // ---- S = scale * Q K^T ----
        f32x4 s4[4];
#pragma unroll
        for (int f = 0; f < 4; ++f) {
            f32x4 a = (f32x4){0.f, 0.f, 0.f, 0.f};
#pragma unroll
            for (int ks = 0; ks < 2; ++ks) {
                int kc = f * 16 + l15;
                bf16x8 kf = *(const bf16x8*)&Kl[kc * 64 + (((ks * 4 + l4) ^ (kc & 7)) * 8)];
                a = __builtin_amdgcn_mfma_f32_16x16x32_bf16(qf[ks], kf, a, 0, 0, 0);
            }
            s4[f] = a * scale;
        }
        // ---- sparse bias ----
        {
            int bs = bstart[qb * 64 + t], be = bstart[qb * 64 + t + 1];
            for (int i = bs; i < be; ++i) {
                int rc = (int)ents[i];
                int r6 = rc >> 6, c6 = rc & 63;
                if ((r6 >> 4) == w && ((r6 >> 2) & 3) == l4 && (c6 & 15) == l15) {
                    float arg = w0 * (float)(qb * 64 + r6) + w1 * (float)(t * 64 + c6) + w2;
                    float sig = 1.f / (1.f + __expf(-arg));
                    switch (((c6 >> 4) << 2) | (r6 & 3)) {
                        case 0:  s4[0][0] += sig; break; case 1:  s4[0][1] += sig; break;
                        case 2:  s4[0][2] += sig; break; case 3:  s4[0][3] += sig; break;
                        case 4:  s4[1][0] += sig; break; case 5:  s4[1][1] += sig; break;
                        case 6:  s4[1][2] += sig; break; case 7:  s4[1][3] += sig; break;
                        case 8:  s4[2][0] += sig; break; case 9:  s4[2][1] += sig; break;
                        case 10: s4[2][2] += sig; break; case 11: s4[2][3] += sig; break;
                        case 12: s4[3][0] += sig; break; case 13: s4[3][1] += sig; break;
                        case 14: s4[3][2] += sig; break; case 15: s4[3][3] += sig; break;
                    }
                }
            }
        }
        // ---- online softmax ----
        float me[4];
#pragma unroll
        for (int j = 0; j < 4; ++j)
            me[j] = fmaxf(fmaxf(s4[0][j], s4[1][j]), fmaxf(s4[2][j], s4[3][j]));
#pragma unroll
        for (int m = 1; m < 16; m <<= 1)
#pragma unroll
            for (int j = 0; j < 4; ++j) me[j] = fmaxf(me[j], __shfl_xor(me[j], m));
        float fac[4];
#pragma unroll
        for (int j = 0; j < 4; ++j) {
            float mn = fmaxf(m_run[j], me[j]);
            fac[j] = __expf(m_run[j] - mn);
            m_run[j] = mn;
        }
        float rs[4] = {0.f, 0.f, 0.f, 0.f};
#pragma unroll
        for (int f = 0; f < 4; ++f)
#pragma unroll
            for (int j = 0; j < 4; ++j) {
                float p = __expf(s4[f][j] - m_run[j]);
                s4[f][j] = p;
                rs[j] += p;
            }
#pragma unroll
        for (int m = 1; m < 16; m <<= 1)
#pragma unroll
            for (int j = 0; j < 4; ++j) rs[j] += __shfl_xor(rs[j], m);
#pragma unroll
        for (int j = 0; j < 4; ++j) l_run[j] = l_run[j] * fac[j] + rs[j];
#pragma unroll
        for (int f = 0; f < 4; ++f)
#pragma unroll
            for (int j = 0; j < 4; ++j) o[f][j] *= fac[j];
        // ---- P -> per-wave LDS (bf16, swizzled) ----
#pragma unroll
        for (int f = 0; f < 4; ++f)
#pragma unroll
            for (int j = 0; j < 4; ++j) {
                int r16 = l4 * 4 + j, c6 = f * 16 + l15;
                P[r16 * 64 + (((c6 >> 3) ^ (r16 & 7)) * 8) + (c6 & 7)] = f2b(s4[f][j]);
            }
        __builtin_amdgcn_s_waitcnt(0);
        // ---- O += P V ----
#pragma unroll
        for (int ks = 0; ks < 2; ++ks) {
            bf16x8 pa = *(const bf16x8*)&P[l15 * 64 + (((ks * 4 + l4) ^ (l15 & 7)) * 8)];
#pragma unroll
            for (int fd = 0; fd < 4; ++fd) {
                int d = fd * 16 + l15;
                bf16x8 vb = *(const bf16x8*)&Vl[d * 64 + (((ks * 4 + l4) ^ (d & 7)) * 8)];
                o[fd] = __builtin_amdgcn_mfma_f32_16x16x32_bf16(pa, vb, o[fd], 0, 0, 0);
            }
        }
        __syncthreads();
    }
    // ---- write partials ----
    long base = (((long)cz * NH + h) * NN + qb * 64 + w * 16) * 64;
#pragma unroll
    for (int fd = 0; fd < 4; ++fd)
#pragma unroll
        for (int j = 0; j < 4; ++j)
            opart[base + (l4 * 4 + j) * 64 + fd * 16 + l15] = o[fd][j];
    if (l15 == 0) {
#pragma unroll
        for (int j = 0; j < 4; ++j)
            ml[((long)cz * NH + h) * NN + qb * 64 + w * 16 + l4 * 4 + j] =
                make_float2(m_run[j], l_run[j]);
    }
}

// merge NCH chunk partials -> attnOb (bf16)
__global__ __launch_bounds__(256) void k_comb(const float* __restrict__ opart,
                                              const float2* __restrict__ ml,
                                              ushort* __restrict__ attnOb) {
    int t = blockIdx.x * 256 + threadIdx.x;  // NN*NH*64 total
    int d = t & 63;
    int r = (t >> 6) & (NN - 1);
    int h = t >> 18;
    float2 mls[NCH];
    float M = -1e30f;
#pragma unroll
    for (int c = 0; c < NCH; ++c) {
        mls[c] = ml[((long)c * NH + h) * NN + r];
        M = fmaxf(M, mls[c].x);
    }
    float s = 0.f, ov = 0.f;
#pragma unroll
    for (int c = 0; c < NCH; ++c) {
        float e = __expf(mls[c].x - M);
        s += mls[c].y * e;
        ov += opart[(((long)c * NH + h) * NN + r) * 64 + d] * e;
    }
    attnOb[(long)r * DM + h * 64 + d] = f2b(ov / s);
}

// ---------------- layernorm / output ----------------

__global__ void k_add_ln(float* __restrict__ x, ushort* __restrict__ xb,
                         const float* __restrict__ y,
                         const float* __restrict__ g, const float* __restrict__ b) {
    int row = blockIdx.x;
    int lane = threadIdx.x;  // 64
    float v[4];
#pragma unroll
    for (int i = 0; i < 4; ++i)
        v[i] = x[(long)row * DM + lane + 64 * i] + y[(long)row * DM + lane + 64 * i];
    float s = v[0] + v[1] + v[2] + v[3];
#pragma unroll
    for (int o = 1; o < 64; o <<= 1) s += __shfl_xor(s, o);
    float m = s * (1.f / 256.f);
    float q = 0.f;
#pragma unroll
    for (int i = 0; i < 4; ++i) { float d = v[i] - m; q += d * d; }
#pragma unroll
    for (int o = 1; o < 64; o <<= 1) q += __shfl_xor(q, o);
    float rs = rsqrtf(q * (1.f / 256.f) + 1e-5f);
#pragma unroll
    for (int i = 0; i < 4; ++i) {
        int c = lane + 64 * i;
        float val = (v[i] - m) * rs * g[c] + b[c];
        x[(long)row * DM + c] = val;
        xb[(long)row * DM + c] = f2b(val);
    }
}

__global__ void k_out(const float* __restrict__ x, const float* __restrict__ w,
                      const float* __restrict__ b, float* __restrict__ out) {
    int row = blockIdx.x;
    int lane = threadIdx.x;
    float s = 0.f;
#pragma unroll
    for (int i = 0; i < 4; ++i) s += x[(long)row * DM + lane + 64 * i] * w[lane + 64 * i];
#pragma unroll
    for (int o = 1; o < 64; o <<= 1) s += __shfl_xor(s, o);
    if (lane == 0) out[row] = 1.f / (1.f + expf(-(s + b[0])));
}

__global__ void k_sentinel(float* out, int n) {
    int i = blockIdx.x * 256 + threadIdx.x;
    if (i < n) out[i] = 1.0e9f;
}

// ---------------- host ----------------

extern "C" void kernel_launch(void* const* d_in, const int* in_sizes, int n_in,
                              void* d_out, int out_size, void* d_ws, size_t ws_size,
                              hipStream_t stream) {
    const float* nf = (const float*)d_in[0];
    const int* ei = (const int*)d_in[1];
    const int* erow = ei;
    const int* ecol = ei + NE;
    const float* gcn1_w = (const float*)d_in[2];
    const float* gcn1_b = (const float*)d_in[3];
    const float* gcn2_w = (const float*)d_in[4];
    const float* gcn2_b = (const float*)d_in[5];
    const float* edge_w = (const float*)d_in[6];
    const float* edge_b = (const float*)d_in[7];
    const float* proj_w = (const float*)d_in[8];
    const float* proj_b = (const float*)d_in[9];
    const float* wqkv = (const float*)d_in[10];
    const float* bqkv = (const float*)d_in[11];
    const float* wo = (const float*)d_in[12];
    const float* bo = (const float*)d_in[13];
    const float* ffn_w1 = (const float*)d_in[14];
    const float* ffn_b1 = (const float*)d_in[15];
    const float* ffn_w2 = (const float*)d_in[16];
    const float* ffn_b2 = (const float*)d_in[17];
    const float* ln1_g = (const float*)d_in[18];
    const float* ln1_b = (const float*)d_in[19];
    const float* ln2_g = (const float*)d_in[20];
    const float* ln2_b = (const float*)d_in[21];
    const float* out_w = (const float*)d_in[22];
    const float* out_b = (const float*)d_in[23];
    float* out = (float*)d_out;

    char* wp = (char*)d_ws;
    size_t off = 0;
    auto alloc = [&](size_t bytes) -> void* {
        void* p = wp + off;
        off = (off + bytes + 255) & ~(size_t)255;
        return p;
    };
    // big union block: msg (GCN) / opart (attn) / ffnH+ybuf (ffn)
    char* big = (char*)alloc((size_t)NCH * NH * NN * 64 * 4);  // 16 MB
    float* msg = (float*)big;
    float* opart = (float*)big;
    ushort* ffnHb = (ushort*)big;                       // 8 MB
    float* ybuf = (float*)(big + (size_t)8 * 1024 * 1024);  // 4 MB
    float* x = (float*)alloc((size_t)NN * DM * 4);
    ushort* xb = (ushort*)alloc((size_t)NN * DM * 2);
    ushort* xcb = (ushort*)alloc((size_t)NN * 384 * 2);
    ushort* hb = (ushort*)alloc((size_t)NN * DM * 2);
    float* g = (float*)alloc((size_t)NN * DM * 4);
    ushort* qkb = (ushort*)alloc((size_t)NN * 512 * 2);
    ushort* vT = (ushort*)alloc((size_t)DM * NN * 2);
    ushort* attnOb = (ushort*)alloc((size_t)NN * DM * 2);
    float2* ml = (float2*)alloc((size_t)NCH * NH * NN * 8);
    ushort* nfb = (ushort*)alloc((size_t)NN * DIN * 2);
    ushort* wqkvb = (ushort*)alloc((size_t)NL * 768 * DM * 2);
    ushort* wob = (ushort*)alloc((size_t)NL * DM * DM * 2);
    ushort* f1b = (ushort*)alloc((size_t)NL * 1024 * DM * 2);
    ushort* f2bw = (ushort*)alloc((size_t)NL * DM * 1024 * 2);
    ushort* g1b = (ushort*)alloc((size_t)DM * DIN * 2);
    ushort* g2b = (ushort*)alloc((size_t)DM * DM * 2);
    ushort* pjb = (ushort*)alloc((size_t)DM * 384 * 2);
    uint* bitmap = (uint*)alloc((size_t)NN * NN / 8);
    unsigned char* flag = (unsigned char*)alloc(NE);
    int* cnt_c = (int*)alloc((size_t)NN * 4);
    int* bcnt = (int*)alloc((size_t)NN * 4);
    int* sc = (int*)alloc((size_t)(NN + 1) * 4);
    int* bstart = (int*)alloc((size_t)(NN + 1) * 4);
    int* fc = (int*)alloc((size_t)NN * 4);
    int* bfill = (int*)alloc((size_t)NN * 4);
    int* csc_row = (int*)alloc((size_t)NE * 4);
    ushort* ents = (ushort*)alloc((size_t)NE * 2);
    float* dinv = (float*)alloc((size_t)NN * 4);

    if (off > ws_size) {
        k_sentinel<<<(out_size + 255) / 256, 256, 0, stream>>>(out, out_size);
        return;
    }

    // ---- preprocessing ----
    hipMemsetAsync(bitmap, 0, (size_t)NN * NN / 8, stream);
    hipMemsetAsync(cnt_c, 0, NN * 4, stream);
    hipMemsetAsync(bcnt, 0, NN * 4, stream);
    hipMemsetAsync(fc, 0, NN * 4, stream);
    hipMemsetAsync(bfill, 0, NN * 4, stream);
    k_edge1<<<NE / 256, 256, 0, stream>>>(erow, ecol, bitmap, cnt_c, bcnt, flag);
    k_scan<<<1, 256, 0, stream>>>(cnt_c, sc);
    k_scan<<<1, 256, 0, stream>>>(bcnt, bstart);
    k_edge2<<<NE / 256, 256, 0, stream>>>(erow, ecol, flag, sc, fc, csc_row, bstart, bfill, ents);
    k_dinv<<<NN / 256, 256, 0, stream>>>(cnt_c, dinv);

    // ---- weight/input conversion ----
    CvtP cp;
    cp.s[0] = nf;      cp.d[0] = nfb;   cp.n[0] = NN * DIN;
    cp.s[1] = wqkv;    cp.d[1] = wqkvb; cp.n[1] = NL * 768 * DM;
    cp.s[2] = wo;      cp.d[2] = wob;   cp.n[2] = NL * DM * DM;
    cp.s[3] = ffn_w1;  cp.d[3] = f1b;   cp.n[3] = NL * 1024 * DM;
    cp.s[4] = ffn_w2;  cp.d[4] = f2bw;  cp.n[4] = NL * DM * 1024;
    cp.s[5] = gcn1_w;  cp.d[5] = g1b;   cp.n[5] = DM * DIN;
    cp.s[6] = gcn2_w;  cp.d[6] = g2b;   cp.n[6] = DM * DM;
    cp.s[7] = proj_w;  cp.d[7] = pjb;   cp.n[7] = DM * 384;
    k_cvt<<<dim3(768, 8), 256, 0, stream>>>(cp);

    // ---- GCN ----
    k_gemm_b<1><<<dim3(DM / 128, NN / 128), 256, 0, stream>>>(
        nfb, DIN, g1b, DIN, msg, nullptr, DM, DIN, nullptr);
    k_gcn_agg<1, 1><<<NN, DM, 0, stream>>>(msg, sc, csc_row, dinv, gcn1_b, nullptr, hb);
    k_gemm_b<1><<<dim3(DM / 128, NN / 128), 256, 0, stream>>>(
        hb, DM, g2b, DM, msg, nullptr, DM, DM, nullptr);
    k_gcn_agg<0, 0><<<NN, DM, 0, stream>>>(msg, sc, csc_row, dinv, gcn2_b, g, nullptr);
    // ---- proj ----
    k_concat<<<(NN * 384 + 255) / 256, 256, 0, stream>>>(nfb, g, xcb);
    k_gemm_b<3><<<dim3(DM / 128, NN / 128), 256, 0, stream>>>(
        xcb, 384, pjb, 384, x, xb, DM, 384, proj_b);

    for (int l = 0; l < NL; ++l) {
        // q,k -> qkb [n][512]; v -> vT [256][NN] transposed
        k_gemm_b<2><<<dim3(512 / 128, NN / 128), 256, 0, stream>>>(
            xb, DM, wqkvb + (long)l * 768 * DM, DM, nullptr, qkb, 512, DM,
            bqkv + (long)l * 768);
        k_gemm_b<8><<<dim3(DM / 128, NN / 128), 256, 0, stream>>>(
            xb, DM, wqkvb + (long)l * 768 * DM + 512 * DM, DM, nullptr, vT, NN, DM,
            bqkv + (long)l * 768 + 512);
        k_attn<<<dim3(NN / 64, NH, NCH), 256, 0, stream>>>(
            qkb, vT, edge_w, edge_b, bstart, ents, opart, ml);
        k_comb<<<NN * NH * 64 / 256, 256, 0, stream>>>(opart, ml, attnOb);
        k_gemm_b<1><<<dim3(DM / 128, NN / 128), 256, 0, stream>>>(
            attnOb, DM, wob + (long)l * DM * DM, DM, ybuf, nullptr, DM, DM,
            bo + (long)l * DM);
        k_add_ln<<<NN, 64, 0, stream>>>(x, xb, ybuf, ln1_g + (long)l * DM, ln1_b + (long)l * DM);
        k_gemm_b<6><<<dim3(1024 / 128, NN / 128), 256, 0, stream>>>(
            xb, DM, f1b + (long)l * 1024 * DM, DM, nullptr, ffnHb, 1024, DM,
            ffn_b1 + (long)l * 1024);
        k_gemm_b<1><<<dim3(DM / 128, NN / 128), 256, 0, stream>>>(
            ffnHb, 1024, f2bw + (long)l * DM * 1024, 1024, ybuf, nullptr, DM, 1024,
            ffn_b2 + (long)l * DM);
        k_add_ln<<<NN, 64, 0, stream>>>(x, xb, ybuf, ln2_g + (long)l * DM, ln2_b + (long)l * DM);
    }
    k_out<<<NN, 64, 0, stream>>>(x, out_w, out_b, out);
}

// Round 4
// 793.359 us; speedup vs baseline: 3.8375x; 1.0305x over previous
//
#include <hip/hip_runtime.h>
#include <math.h>

#define NN 4096
#define NE 65536
#define DIN 128
#define DM 256
#define NH 4
#define NL 3
#define NCH 8
#define TPC (NN / 64 / NCH)  // 8 KV tiles per chunk
#define NBKT 16384           // bias buckets: (r>>4) * 64 + (c>>6)

typedef __attribute__((ext_vector_type(8))) short bf16x8;
typedef __attribute__((ext_vector_type(4))) float f32x4;

__device__ inline ushort f2b(float f) {
    union { float f; uint u; } v; v.f = f;
    uint r = v.u + 0x7fffu + ((v.u >> 16) & 1u);
    return (ushort)(r >> 16);
}

// ---------------- preprocessing ----------------

__global__ void k_edge1(const int* __restrict__ row, const int* __restrict__ col,
                        uint* __restrict__ bitmap, int* __restrict__ cnt_c,
                        int* __restrict__ bcnt, unsigned char* __restrict__ flag) {
    int e = blockIdx.x * 256 + threadIdx.x;
    if (e >= NE) return;
    int r = row[e], c = col[e];
    atomicAdd(&cnt_c[c], 1);
    uint idx = (uint)r * 4096u + (uint)c;
    uint m = 1u << (idx & 31);
    uint old = atomicOr(&bitmap[idx >> 5], m);
    int isnew = (old & m) ? 0 : 1;
    flag[e] = (unsigned char)isnew;
    if (isnew) atomicAdd(&bcnt[(r >> 4) * 64 + (c >> 6)], 1);
}

__global__ void k_edge2(const int* __restrict__ row, const int* __restrict__ col,
                        const unsigned char* __restrict__ flag,
                        const int* __restrict__ sc, int* __restrict__ fc, int* __restrict__ csc_row,
                        const int* __restrict__ bstart, int* __restrict__ bfill,
                        ushort* __restrict__ ents) {
    int e = blockIdx.x * 256 + threadIdx.x;
    if (e >= NE) return;
    int r = row[e], c = col[e];
    csc_row[sc[c] + atomicAdd(&fc[c], 1)] = r;
    if (flag[e]) {
        int key = (r >> 4) * 64 + (c >> 6);
        ents[bstart[key] + atomicAdd(&bfill[key], 1)] = (ushort)(((r & 15) << 6) | (c & 63));
    }
}

// exclusive scan of N ints -> start[0..N]
template <int N>
__global__ void k_scan(const int* __restrict__ cnt, int* __restrict__ start) {
    __shared__ int part[256];
    const int C = N / 256;
    int t = threadIdx.x;
    int s = 0;
    for (int i = 0; i < C; ++i) s += cnt[t * C + i];
    part[t] = s;
    __syncthreads();
    if (t == 0) {
        int acc = 0;
        for (int i = 0; i < 256; ++i) { int v = part[i]; part[i] = acc; acc += v; }
        start[N] = acc;
    }
    __syncthreads();
    int acc = part[t];
    for (int i = 0; i < C; ++i) { start[t * C + i] = acc; acc += cnt[t * C + i]; }
}

__global__ void k_dinv(const int* __restrict__ cnt_c, float* __restrict__ dinv) {
    int i = blockIdx.x * 256 + threadIdx.x;
    if (i < NN) dinv[i] = 1.0f / sqrtf((float)(cnt_c[i] + 1));
}

// ---------------- f32 -> bf16 batch convert ----------------
struct CvtP { const float* s[8]; ushort* d[8]; int n[8]; };
__global__ void k_cvt(CvtP p) {
    int y = blockIdx.y;
    int base = (blockIdx.x * 256 + threadIdx.x) * 4;
    if (base >= p.n[y]) return;
    float4 v = *(const float4*)(p.s[y] + base);
    ushort4 o;
    o.x = f2b(v.x); o.y = f2b(v.y); o.z = f2b(v.z); o.w = f2b(v.w);
    *(ushort4*)(p.d[y] + base) = o;
}

// ---------------- bf16 MFMA GEMM: C = act(A @ B^T + bias) ----------------
// FLAGS: 1 = write f32 Cf, 2 = write bf16 Cb, 4 = relu, 8 = write bf16 TRANSPOSED (Cb[c*ldc + r])
template <int FLAGS>
__global__ __launch_bounds__(256) void k_gemm_b(
    const ushort* __restrict__ A, int lda,
    const ushort* __restrict__ B, int ldb,
    float* __restrict__ Cf, ushort* __restrict__ Cb, int ldc,
    int K, const float* __restrict__ bias) {
    __shared__ ushort As[128 * 64];
    __shared__ ushort Bs[128 * 64];
    const int tid = threadIdx.x;
    const int w = tid >> 6, l = tid & 63;
    const int l15 = l & 15, l4 = l >> 4;
    const int row0 = blockIdx.y * 128, col0 = blockIdx.x * 128;
    const int wm = (w >> 1) * 64, wn = (w & 1) * 64;
    f32x4 acc[4][4];
#pragma unroll
    for (int i = 0; i < 4; ++i)
#pragma unroll
        for (int j = 0; j < 4; ++j) acc[i][j] = (f32x4){0.f, 0.f, 0.f, 0.f};
    for (int k0 = 0; k0 < K; k0 += 64) {
#pragma unroll
        for (int i = 0; i < 4; ++i) {
            int ci = tid + 256 * i;
            int r = ci >> 3, s = ci & 7;
            bf16x8 va = *(const bf16x8*)(A + (long)(row0 + r) * lda + k0 + s * 8);
            *(bf16x8*)&As[r * 64 + ((s ^ (r & 7)) * 8)] = va;
            bf16x8 vb = *(const bf16x8*)(B + (long)(col0 + r) * ldb + k0 + s * 8);
            *(bf16x8*)&Bs[r * 64 + ((s ^ (r & 7)) * 8)] = vb;
        }
        __syncthreads();
#pragma unroll
        for (int kk = 0; kk < 2; ++kk) {
            bf16x8 af[4], bfr[4];
#pragma unroll
            for (int i = 0; i < 4; ++i) {
                int ar = wm + i * 16 + l15;
                af[i] = *(const bf16x8*)&As[ar * 64 + (((kk * 4 + l4) ^ (ar & 7)) * 8)];
                int br = wn + i * 16 + l15;
                bfr[i] = *(const bf16x8*)&Bs[br * 64 + (((kk * 4 + l4) ^ (br & 7)) * 8)];
            }
#pragma unroll
            for (int i = 0; i < 4; ++i)
#pragma unroll
                for (int j = 0; j < 4; ++j)
                    acc[i][j] = __builtin_amdgcn_mfma_f32_16x16x32_bf16(af[i], bfr[j], acc[i][j], 0, 0, 0);
        }
        __syncthreads();
    }
#pragma unroll
    for (int i = 0; i < 4; ++i)
#pragma unroll
        for (int j = 0; j < 4; ++j) {
            int rb = row0 + wm + i * 16;
            int cb = col0 + wn + j * 16 + l15;
            float bv = bias ? bias[cb] : 0.f;
            if (FLAGS & 8) {
                ushort4 o4;
                o4.x = f2b(acc[i][j][0] + bv);
                o4.y = f2b(acc[i][j][1] + bv);
                o4.z = f2b(acc[i][j][2] + bv);
                o4.w = f2b(acc[i][j][3] + bv);
                *(ushort4*)(Cb + (long)cb * ldc + rb + l4 * 4) = o4;
            } else {
#pragma unroll
                for (int q = 0; q < 4; ++q) {
                    int r = rb + l4 * 4 + q;
                    float v = acc[i][j][q] + bv;
                    if (FLAGS & 4) v = fmaxf(v, 0.f);
                    if (FLAGS & 1) Cf[(long)r * ldc + cb] = v;
                    if (FLAGS & 2) Cb[(long)r * ldc + cb] = f2b(v);
                }
            }
        }
}

// ---------------- GCN aggregation ----------------
template <int ACT, int B16>
__global__ void k_gcn_agg(const float* __restrict__ msg, const int* __restrict__ sc,
                          const int* __restrict__ csc_row, const float* __restrict__ dinv,
                          const float* __restrict__ bias,
                          float* __restrict__ outf, ushort* __restrict__ outb) {
    int j = blockIdx.x;
    int d = threadIdx.x;
    float acc = 0.f;
    int a = sc[j], b = sc[j + 1];
    for (int i = a; i < b; ++i) {
        int r = csc_row[i];
        acc += dinv[r] * msg[(long)r * DM + d];
    }
    float dj = dinv[j];
    float v = dj * acc + dj * dj * msg[(long)j * DM + d] + bias[d];
    if (ACT) v = fmaxf(v, 0.f);
    if (B16) outb[(long)j * DM + d] = f2b(v);
    else outf[(long)j * DM + d] = v;
}

__global__ void k_concat(const ushort* __restrict__ nfb, const float* __restrict__ g,
                         ushort* __restrict__ xcb) {
    long i = (long)blockIdx.x * 256 + threadIdx.x;
    if (i >= (long)NN * 384) return;
    int r = (int)(i / 384), c = (int)(i % 384);
    xcb[i] = (c < DIN) ? nfb[(long)r * DIN + c] : f2b(g[(long)r * DM + (c - DIN)]);
}

// ---------------- barrier-free flash attention, KV-split into NCH chunks ----------------
// grid: (NN/64, NH, NCH). 4 waves; wave w owns q-rows qb*64+w*16..+15, fully independent.
// K/V fragments loaded DIRECTLY from global (L2-hot); LDS only for per-wave P transpose.
__global__ __launch_bounds__(256) void k_attn(
    const ushort* __restrict__ qkb, const ushort* __restrict__ vT,
    const float* __restrict__ ew, const float* __restrict__ eb,
    const int* __restrict__ bstart, const ushort* __restrict__ ents,
    float* __restrict__ opart, float2* __restrict__ ml) {
    __shared__ ushort Pl[4 * 16 * 64];  // 8 KB, per-wave slices
    const int qb = blockIdx.x, h = blockIdx.y, cz = blockIdx.z;
    const int tid = threadIdx.x, w = tid >> 6, l = tid & 63;
    const int l15 = l & 15, l4 = l >> 4;
    const float w0 = ew[h * 3 + 0], w1 = ew[h * 3 + 1], w2 = ew[h * 3 + 2] + eb[h];
    const float scale = 0.125f;
    bf16x8 qf[2];
    {
        const ushort* qp = qkb + (long)(qb * 64 + w * 16 + l15) * 512 + h * 64 + l4 * 8;
        qf[0] = *(const bf16x8*)(qp);
        qf[1] = *(const bf16x8*)(qp + 32);
    }
    const ushort* Kb = qkb + 256 + h * 64;          // row stride 512
    const ushort* Vb = vT + (long)(h * 64) * NN;    // row stride NN
    f32x4 o[4];
#pragma unroll
    for (int f = 0; f < 4; ++f) o[f] = (f32x4){0.f, 0.f, 0.f, 0.f};
    float m_run[4], l_run[4];
#pragma unroll
    for (int j = 0; j < 4; ++j) { m_run[j] = -1e30f; l_run[j] = 0.f; }
    ushort* P = &Pl[w * 1024];
    const int bktbase = (qb * 4 + w) * 64;

    for (int t = cz * TPC; t < cz * TPC + TPC; ++t) {
        // ---- K fragments direct from global; S = scale * Q K^T ----
        f32x4 s4[4];
#pragma unroll
        for (int f = 0; f < 4; ++f) {
            const ushort* kp = Kb + (long)(t * 64 + f * 16 + l15) * 512 + l4 * 8;
            bf16x8 k0 = *(const bf16x8*)(kp);
            bf16x8 k1 = *(const bf16x8*)(kp + 32);
            f32x4 a = (f32x4){0.f, 0.f, 0.f, 0.f};
            a = __builtin_amdgcn_mfma_f32_16x16x32_bf16(qf[0], k0, a, 0, 0, 0);
            a = __builtin_amdgcn_mfma_f32_16x16x32_bf16(qf[1], k1, a, 0, 0, 0);
            s4[f] = a * scale;
        }
        // ---- sparse bias (per-wave bucket, ~4 entries) ----
        {
            int bs = bstart[bktbase + t], be = bstart[bktbase + t + 1];
            for (int i = bs; i < be; ++i) {
                int rc = (int)ents[i];
                int r4 = rc >> 6, c6 = rc & 63;
                if ((r4 >> 2) == l4 && (c6 & 15) == l15) {
                    float arg = w0 * (float)(qb * 64 + w * 16 + r4) + w1 * (float)(t * 64 + c6) + w2;
                    float sig = 1.f / (1.f + __expf(-arg));
                    switch (((c6 >> 4) << 2) | (r4 & 3)) {
                        case 0:  s4[0][0] += sig; break; case 1:  s4[0][1] += sig; break;
                        case 2:  s4[0][2] += sig; break; case 3:  s4[0][3] += sig; break;
                        case 4:  s4[1][0] += sig; break; case 5:  s4[1][1] += sig; break;
                        case 6:  s4[1][2] += sig; break; case 7:  s4[1][3] += sig; break;
                        case 8:  s4[2][0] += sig; break; case 9:  s4[2][1] += sig; break;
                        case 10: s4[2][2] += sig; break; case 11: s4[2][3] += sig; break;
                        case 12: s4[3][0] += sig; break; case 13: s4[3][1] += sig; break;
                        case 14: s4[3][2] += sig; break; case 15: s4[3][3] += sig; break;
                    }
                }
            }
        }
        // ---- online softmax ----
        float me[4];
#pragma unroll
        for (int j = 0; j < 4; ++j)
            me[j] = fmaxf(fmaxf(s4[0][j], s4[1][j]), fmaxf(s4[2][j], s4[3][j]));
#pragma unroll
        for (int m = 1; m < 16; m <<= 1)
#pragma unroll
            for (int j = 0; j < 4; ++j) me[j] = fmaxf(me[j], __shfl_xor(me[j], m));
        float fac[4];
#pragma unroll
        for (int j = 0; j < 4; ++j) {
            float mn = fmaxf(m_run[j], me[j]);
            fac[j] = __expf(m_run[j] - mn);
            m_run[j] = mn;
        }
        float rs[4] = {0.f, 0.f, 0.f, 0.f};
#pragma unroll
        for (int f = 0; f < 4; ++f)
#pragma unroll
            for (int j = 0; j < 4; ++j) {
                float p = __expf(s4[f][j] - m_run[j]);
                s4[f][j] = p;
                rs[j] += p;
            }
#pragma unroll
        for (int m = 1; m < 16; m <<= 1)
#pragma unroll
            for (int j = 0; j < 4; ++j) rs[j] += __shfl_xor(rs[j], m);
#pragma unroll
        for (int j = 0; j < 4; ++j) l_run[j] = l_run[j] * fac[j] + rs[j];
#pragma unroll
        for (int f = 0; f < 4; ++f)
#pragma unroll
            for (int j = 0; j < 4; ++j) o[f][j] *= fac[j];
        // ---- P -> per-wave LDS (bf16, swizzled) ----
#pragma unroll
        for (int f = 0; f < 4; ++f)
#pragma unroll
            for (int j = 0; j < 4; ++j) {
                int r16 = l4 * 4 + j, c6 = f * 16 + l15;
                P[r16 * 64 + (((c6 >> 3) ^ (r16 & 7)) * 8) + (c6 & 7)] = f2b(s4[f][j]);
            }
        __builtin_amdgcn_s_waitcnt(0);  // P writes visible to own wave
        // ---- O += P V  (V fragments direct from global vT) ----
#pragma unroll
        for (int ks = 0; ks < 2; ++ks) {
            bf16x8 pa = *(const bf16x8*)&P[l15 * 64 + (((ks * 4 + l4) ^ (l15 & 7)) * 8)];
#pragma unroll
            for (int fd = 0; fd < 4; ++fd) {
                bf16x8 vf = *(const bf16x8*)(Vb + (long)(fd * 16 + l15) * NN + t * 64 + ks * 32 + l4 * 8);
                o[fd] = __builtin_amdgcn_mfma_f32_16x16x32_bf16(pa, vf, o[fd], 0, 0, 0);
            }
        }
    }
    // ---- write partials ----
    long base = (((long)cz * NH + h) * NN + qb * 64 + w * 16) * 64;
#pragma unroll
    for (int fd = 0; fd < 4; ++fd)
#pragma unroll
        for (int j = 0; j < 4; ++j)
            opart[base + (l4 * 4 + j) * 64 + fd * 16 + l15] = o[fd][j];
    if (l15 == 0) {
#pragma unroll
        for (int j = 0; j < 4; ++j)
            ml[((long)cz * NH + h) * NN + qb * 64 + w * 16 + l4 * 4 + j] =
                make_float2(m_run[j], l_run[j]);
    }
}

// merge NCH chunk partials -> attnOb (bf16)
__global__ __launch_bounds__(256) void k_comb(const float* __restrict__ opart,
                                              const float2* __restrict__ ml,
                                              ushort* __restrict__ attnOb) {
    int t = blockIdx.x * 256 + threadIdx.x;  // NN*NH*64 total
    int d = t & 63;
    int r = (t >> 6) & (NN - 1);
    int h = t >> 18;
    float2 mls[NCH];
    float M = -1e30f;
#pragma unroll
    for (int c = 0; c < NCH; ++c) {
        mls[c] = ml[((long)c * NH + h) * NN + r];
        M = fmaxf(M, mls[c].x);
    }
    float s = 0.f, ov = 0.f;
#pragma unroll
    for (int c = 0; c < NCH; ++c) {
        float e = __expf(mls[c].x - M);
        s += mls[c].y * e;
        ov += opart[(((long)c * NH + h) * NN + r) * 64 + d] * e;
    }
    attnOb[(long)r * DM + h * 64 + d] = f2b(ov / s);
}

// ---------------- layernorm / output ----------------

__global__ __launch_bounds__(256) void k_add_ln(
    float* __restrict__ x, ushort* __restrict__ xb, const float* __restrict__ y,
    const float* __restrict__ g, const float* __restrict__ b) {
    int row = blockIdx.x * 4 + (threadIdx.x >> 6);
    int lane = threadIdx.x & 63;
    float v[4];
#pragma unroll
    for (int i = 0; i < 4; ++i)
        v[i] = x[(long)row * DM + lane + 64 * i] + y[(long)row * DM + lane + 64 * i];
    float s = v[0] + v[1] + v[2] + v[3];
#pragma unroll
    for (int o = 1; o < 64; o <<= 1) s += __shfl_xor(s, o);
    float m = s * (1.f / 256.f);
    float q = 0.f;
#pragma unroll
    for (int i = 0; i < 4; ++i) { float d = v[i] - m; q += d * d; }
#pragma unroll
    for (int o = 1; o < 64; o <<= 1) q += __shfl_xor(q, o);
    float rs = rsqrtf(q * (1.f / 256.f) + 1e-5f);
#pragma unroll
    for (int i = 0; i < 4; ++i) {
        int c = lane + 64 * i;
        float val = (v[i] - m) * rs * g[c] + b[c];
        x[(long)row * DM + c] = val;
        xb[(long)row * DM + c] = f2b(val);
    }
}

__global__ void k_out(const float* __restrict__ x, const float* __restrict__ w,
                      const float* __restrict__ b, float* __restrict__ out) {
    int row = blockIdx.x;
    int lane = threadIdx.x;
    float s = 0.f;
#pragma unroll
    for (int i = 0; i < 4; ++i) s += x[(long)row * DM + lane + 64 * i] * w[lane + 64 * i];
#pragma unroll
    for (int o = 1; o < 64; o <<= 1) s += __shfl_xor(s, o);
    if (lane == 0) out[row] = 1.f / (1.f + expf(-(s + b[0])));
}

__global__ void k_sentinel(float* out, int n) {
    int i = blockIdx.x * 256 + threadIdx.x;
    if (i < n) out[i] = 1.0e9f;
}

// ---------------- host ----------------

extern "C" void kernel_launch(void* const* d_in, const int* in_sizes, int n_in,
                              void* d_out, int out_size, void* d_ws, size_t ws_size,
                              hipStream_t stream) {
    const float* nf = (const float*)d_in[0];
    const int* ei = (const int*)d_in[1];
    const int* erow = ei;
    const int* ecol = ei + NE;
    const float* gcn1_w = (const float*)d_in[2];
    const float* gcn1_b = (const float*)d_in[3];
    const float* gcn2_w = (const float*)d_in[4];
    const float* gcn2_b = (const float*)d_in[5];
    const float* edge_w = (const float*)d_in[6];
    const float* edge_b = (const float*)d_in[7];
    const float* proj_w = (const float*)d_in[8];
    const float* proj_b = (const float*)d_in[9];
    const float* wqkv = (const float*)d_in[10];
    const float* bqkv = (const float*)d_in[11];
    const float* wo = (const float*)d_in[12];
    const float* bo = (const float*)d_in[13];
    const float* ffn_w1 = (const float*)d_in[14];
    const float* ffn_b1 = (const float*)d_in[15];
    const float* ffn_w2 = (const float*)d_in[16];
    const float* ffn_b2 = (const float*)d_in[17];
    const float* ln1_g = (const float*)d_in[18];
    const float* ln1_b = (const float*)d_in[19];
    const float* ln2_g = (const float*)d_in[20];
    const float* ln2_b = (const float*)d_in[21];
    const float* out_w = (const float*)d_in[22];
    const float* out_b = (const float*)d_in[23];
    float* out = (float*)d_out;

    char* wp = (char*)d_ws;
    size_t off = 0;
    auto alloc = [&](size_t bytes) -> void* {
        void* p = wp + off;
        off = (off + bytes + 255) & ~(size_t)255;
        return p;
    };
    // big union block (32 MB): msg (GCN) / opart (attn) / ffnHb+ybuf (ffn)
    char* big = (char*)alloc((size_t)NCH * NH * NN * 64 * 4);
    float* msg = (float*)big;
    float* opart = (float*)big;
    ushort* ffnHb = (ushort*)big;                           // 8 MB
    float* ybuf = (float*)(big + (size_t)8 * 1024 * 1024);  // 4 MB
    float* x = (float*)alloc((size_t)NN * DM * 4);
    ushort* xb = (ushort*)alloc((size_t)NN * DM * 2);
    ushort* xcb = (ushort*)alloc((size_t)NN * 384 * 2);
    ushort* hb = (ushort*)alloc((size_t)NN * DM * 2);
    float* g = (float*)alloc((size_t)NN * DM * 4);
    ushort* qkb = (ushort*)alloc((size_t)NN * 512 * 2);
    ushort* vT = (ushort*)alloc((size_t)DM * NN * 2);
    ushort* attnOb = (ushort*)alloc((size_t)NN * DM * 2);
    float2* ml = (float2*)alloc((size_t)NCH * NH * NN * 8);
    ushort* nfb = (ushort*)alloc((size_t)NN * DIN * 2);
    ushort* wqkvb = (ushort*)alloc((size_t)NL * 768 * DM * 2);
    ushort* wob = (ushort*)alloc((size_t)NL * DM * DM * 2);
    ushort* f1b = (ushort*)alloc((size_t)NL * 1024 * DM * 2);
    ushort* f2bw = (ushort*)alloc((size_t)NL * DM * 1024 * 2);
    ushort* g1b = (ushort*)alloc((size_t)DM * DIN * 2);
    ushort* g2b = (ushort*)alloc((size_t)DM * DM * 2);
    ushort* pjb = (ushort*)alloc((size_t)DM * 384 * 2);
    uint* bitmap = (uint*)alloc((size_t)NN * NN / 8);
    unsigned char* flag = (unsigned char*)alloc(NE);
    int* cnt_c = (int*)alloc((size_t)NN * 4);
    int* bcnt = (int*)alloc((size_t)NBKT * 4);
    int* sc = (int*)alloc((size_t)(NN + 1) * 4);
    int* bstart = (int*)alloc((size_t)(NBKT + 1) * 4);
    int* fc = (int*)alloc((size_t)NN * 4);
    int* bfill = (int*)alloc((size_t)NBKT * 4);
    int* csc_row = (int*)alloc((size_t)NE * 4);
    ushort* ents = (ushort*)alloc((size_t)NE * 2);
    float* dinv = (float*)alloc((size_t)NN * 4);

    if (off > ws_size) {
        k_sentinel<<<(out_size + 255) / 256, 256, 0, stream>>>(out, out_size);
        return;
    }

    // ---- preprocessing ----
    hipMemsetAsync(bitmap, 0, (size_t)NN * NN / 8, stream);
    hipMemsetAsync(cnt_c, 0, NN * 4, stream);
    hipMemsetAsync(bcnt, 0, NBKT * 4, stream);
    hipMemsetAsync(fc, 0, NN * 4, stream);
    hipMemsetAsync(bfill, 0, NBKT * 4, stream);
    k_edge1<<<NE / 256, 256, 0, stream>>>(erow, ecol, bitmap, cnt_c, bcnt, flag);
    k_scan<NN><<<1, 256, 0, stream>>>(cnt_c, sc);
    k_scan<NBKT><<<1, 256, 0, stream>>>(bcnt, bstart);
    k_edge2<<<NE / 256, 256, 0, stream>>>(erow, ecol, flag, sc, fc, csc_row, bstart, bfill, ents);
    k_dinv<<<NN / 256, 256, 0, stream>>>(cnt_c, dinv);

    // ---- weight/input conversion ----
    CvtP cp;
    cp.s[0] = nf;      cp.d[0] = nfb;   cp.n[0] = NN * DIN;
    cp.s[1] = wqkv;    cp.d[1] = wqkvb; cp.n[1] = NL * 768 * DM;
    cp.s[2] = wo;      cp.d[2] = wob;   cp.n[2] = NL * DM * DM;
    cp.s[3] = ffn_w1;  cp.d[3] = f1b;   cp.n[3] = NL * 1024 * DM;
    cp.s[4] = ffn_w2;  cp.d[4] = f2bw;  cp.n[4] = NL * DM * 1024;
    cp.s[5] = gcn1_w;  cp.d[5] = g1b;   cp.n[5] = DM * DIN;
    cp.s[6] = gcn2_w;  cp.d[6] = g2b;   cp.n[6] = DM * DM;
    cp.s[7] = proj_w;  cp.d[7] = pjb;   cp.n[7] = DM * 384;
    k_cvt<<<dim3(768, 8), 256, 0, stream>>>(cp);

    // ---- GCN ----
    k_gemm_b<1><<<dim3(DM / 128, NN / 128), 256, 0, stream>>>(
        nfb, DIN, g1b, DIN, msg, nullptr, DM, DIN, nullptr);
    k_gcn_agg<1, 1><<<NN, DM, 0, stream>>>(msg, sc, csc_row, dinv, gcn1_b, nullptr, hb);
    k_gemm_b<1><<<dim3(DM / 128, NN / 128), 256, 0, stream>>>(
        hb, DM, g2b, DM, msg, nullptr, DM, DM, nullptr);
    k_gcn_agg<0, 0><<<NN, DM, 0, stream>>>(msg, sc, csc_row, dinv, gcn2_b, g, nullptr);
    // ---- proj ----
    k_concat<<<(NN * 384 + 255) / 256, 256, 0, stream>>>(nfb, g, xcb);
    k_gemm_b<3><<<dim3(DM / 128, NN / 128), 256, 0, stream>>>(
        xcb, 384, pjb, 384, x, xb, DM, 384, proj_b);

    for (int l = 0; l < NL; ++l) {
        // q,k -> qkb [n][512]; v -> vT [256][NN] transposed
        k_gemm_b<2><<<dim3(512 / 128, NN / 128), 256, 0, stream>>>(
            xb, DM, wqkvb + (long)l * 768 * DM, DM, nullptr, qkb, 512, DM,
            bqkv + (long)l * 768);
        k_gemm_b<8><<<dim3(DM / 128, NN / 128), 256, 0, stream>>>(
            xb, DM, wqkvb + (long)l * 768 * DM + 512 * DM, DM, nullptr, vT, NN, DM,
            bqkv + (long)l * 768 + 512);
        k_attn<<<dim3(NN / 64, NH, NCH), 256, 0, stream>>>(
            qkb, vT, edge_w, edge_b, bstart, ents, opart, ml);
        k_comb<<<NN * NH * 64 / 256, 256, 0, stream>>>(opart, ml, attnOb);
        k_gemm_b<1><<<dim3(DM / 128, NN / 128), 256, 0, stream>>>(
            attnOb, DM, wob + (long)l * DM * DM, DM, ybuf, nullptr, DM, DM,
            bo + (long)l * DM);
        k_add_ln<<<NN / 4, 256, 0, stream>>>(x, xb, ybuf, ln1_g + (long)l * DM, ln1_b + (long)l * DM);
        k_gemm_b<6><<<dim3(1024 / 128, NN / 128), 256, 0, stream>>>(
            xb, DM, f1b + (long)l * 1024 * DM, DM, nullptr, ffnHb, 1024, DM,
            ffn_b1 + (long)l * 1024);
        k_gemm_b<1><<<dim3(DM / 128, NN / 128), 256, 0, stream>>>(
            ffnHb, 1024, f2bw + (long)l * DM * 1024, 1024, ybuf, nullptr, DM, 1024,
            ffn_b2 + (long)l * DM);
        k_add_ln<<<NN / 4, 256, 0, stream>>>(x, xb, ybuf, ln2_g + (long)l * DM, ln2_b + (long)l * DM);
    }
    k_out<<<NN, 64, 0, stream>>>(x, out_w, out_b, out);
}

// Round 5
// 774.002 us; speedup vs baseline: 3.9335x; 1.0250x over previous
//
#include <hip/hip_runtime.h>
#include <math.h>

#define NN 4096
#define NE 65536
#define DIN 128
#define DM 256
#define NH 4
#define NL 3
#define NCH 8
#define TPC (NN / 64 / NCH)  // 8 KV tiles per chunk
#define NBKT 16384           // bias buckets: (r>>4) * 64 + (c>>6)

typedef __attribute__((ext_vector_type(8))) short bf16x8;
typedef __attribute__((ext_vector_type(4))) float f32x4;

__device__ inline ushort f2b(float f) {
    union { float f; uint u; } v; v.f = f;
    uint r = v.u + 0x7fffu + ((v.u >> 16) & 1u);
    return (ushort)(r >> 16);
}

__device__ inline uint cvt_pk_bf16(float lo, float hi) {
    uint r;
    asm("v_cvt_pk_bf16_f32 %0, %1, %2" : "=v"(r) : "v"(lo), "v"(hi));
    return r;
}

// ---------------- preprocessing ----------------

__global__ void k_edge1(const int* __restrict__ row, const int* __restrict__ col,
                        uint* __restrict__ bitmap, int* __restrict__ cnt_c,
                        int* __restrict__ bcnt, unsigned char* __restrict__ flag) {
    int e = blockIdx.x * 256 + threadIdx.x;
    if (e >= NE) return;
    int r = row[e], c = col[e];
    atomicAdd(&cnt_c[c], 1);
    uint idx = (uint)r * 4096u + (uint)c;
    uint m = 1u << (idx & 31);
    uint old = atomicOr(&bitmap[idx >> 5], m);
    int isnew = (old & m) ? 0 : 1;
    flag[e] = (unsigned char)isnew;
    if (isnew) atomicAdd(&bcnt[(r >> 4) * 64 + (c >> 6)], 1);
}

__global__ void k_edge2(const int* __restrict__ row, const int* __restrict__ col,
                        const unsigned char* __restrict__ flag,
                        const int* __restrict__ sc, int* __restrict__ fc, int* __restrict__ csc_row,
                        const int* __restrict__ bstart, int* __restrict__ bfill,
                        ushort* __restrict__ ents) {
    int e = blockIdx.x * 256 + threadIdx.x;
    if (e >= NE) return;
    int r = row[e], c = col[e];
    csc_row[sc[c] + atomicAdd(&fc[c], 1)] = r;
    if (flag[e]) {
        int key = (r >> 4) * 64 + (c >> 6);
        ents[bstart[key] + atomicAdd(&bfill[key], 1)] = (ushort)(((r & 15) << 6) | (c & 63));
    }
}

// exclusive scan of N ints -> start[0..N]
template <int N>
__global__ void k_scan(const int* __restrict__ cnt, int* __restrict__ start) {
    __shared__ int part[256];
    const int C = N / 256;
    int t = threadIdx.x;
    int s = 0;
    for (int i = 0; i < C; ++i) s += cnt[t * C + i];
    part[t] = s;
    __syncthreads();
    if (t == 0) {
        int acc = 0;
        for (int i = 0; i < 256; ++i) { int v = part[i]; part[i] = acc; acc += v; }
        start[N] = acc;
    }
    __syncthreads();
    int acc = part[t];
    for (int i = 0; i < C; ++i) { start[t * C + i] = acc; acc += cnt[t * C + i]; }
}

__global__ void k_dinv(const int* __restrict__ cnt_c, float* __restrict__ dinv) {
    int i = blockIdx.x * 256 + threadIdx.x;
    if (i < NN) dinv[i] = 1.0f / sqrtf((float)(cnt_c[i] + 1));
}

// ---------------- f32 -> bf16 batch convert ----------------
struct CvtP { const float* s[8]; ushort* d[8]; int n[8]; };
__global__ void k_cvt(CvtP p) {
    int y = blockIdx.y;
    int base = (blockIdx.x * 256 + threadIdx.x) * 4;
    if (base >= p.n[y]) return;
    float4 v = *(const float4*)(p.s[y] + base);
    ushort4 o;
    o.x = f2b(v.x); o.y = f2b(v.y); o.z = f2b(v.z); o.w = f2b(v.w);
    *(ushort4*)(p.d[y] + base) = o;
}

// ---------------- bf16 MFMA GEMM: C = act(A @ B^T + bias) ----------------
// FLAGS: 1 = write f32 Cf, 2 = write bf16 Cb, 4 = relu, 8 = write bf16 TRANSPOSED (Cb[c*ldc + r])
template <int FLAGS>
__global__ __launch_bounds__(256) void k_gemm_b(
    const ushort* __restrict__ A, int lda,
    const ushort* __restrict__ B, int ldb,
    float* __restrict__ Cf, ushort* __restrict__ Cb, int ldc,
    int K, const float* __restrict__ bias) {
    __shared__ ushort As[128 * 64];
    __shared__ ushort Bs[128 * 64];
    const int tid = threadIdx.x;
    const int w = tid >> 6, l = tid & 63;
    const int l15 = l & 15, l4 = l >> 4;
    const int row0 = blockIdx.y * 128, col0 = blockIdx.x * 128;
    const int wm = (w >> 1) * 64, wn = (w & 1) * 64;
    f32x4 acc[4][4];
#pragma unroll
    for (int i = 0; i < 4; ++i)
#pragma unroll
        for (int j = 0; j < 4; ++j) acc[i][j] = (f32x4){0.f, 0.f, 0.f, 0.f};
    for (int k0 = 0; k0 < K; k0 += 64) {
#pragma unroll
        for (int i = 0; i < 4; ++i) {
            int ci = tid + 256 * i;
            int r = ci >> 3, s = ci & 7;
            bf16x8 va = *(const bf16x8*)(A + (long)(row0 + r) * lda + k0 + s * 8);
            *(bf16x8*)&As[r * 64 + ((s ^ (r & 7)) * 8)] = va;
            bf16x8 vb = *(const bf16x8*)(B + (long)(col0 + r) * ldb + k0 + s * 8);
            *(bf16x8*)&Bs[r * 64 + ((s ^ (r & 7)) * 8)] = vb;
        }
        __syncthreads();
#pragma unroll
        for (int kk = 0; kk < 2; ++kk) {
            bf16x8 af[4], bfr[4];
#pragma unroll
            for (int i = 0; i < 4; ++i) {
                int ar = wm + i * 16 + l15;
                af[i] = *(const bf16x8*)&As[ar * 64 + (((kk * 4 + l4) ^ (ar & 7)) * 8)];
                int br = wn + i * 16 + l15;
                bfr[i] = *(const bf16x8*)&Bs[br * 64 + (((kk * 4 + l4) ^ (br & 7)) * 8)];
            }
#pragma unroll
            for (int i = 0; i < 4; ++i)
#pragma unroll
                for (int j = 0; j < 4; ++j)
                    acc[i][j] = __builtin_amdgcn_mfma_f32_16x16x32_bf16(af[i], bfr[j], acc[i][j], 0, 0, 0);
        }
        __syncthreads();
    }
#pragma unroll
    for (int i = 0; i < 4; ++i)
#pragma unroll
        for (int j = 0; j < 4; ++j) {
            int rb = row0 + wm + i * 16;
            int cb = col0 + wn + j * 16 + l15;
            float bv = bias ? bias[cb] : 0.f;
            if (FLAGS & 8) {
                ushort4 o4;
                o4.x = f2b(acc[i][j][0] + bv);
                o4.y = f2b(acc[i][j][1] + bv);
                o4.z = f2b(acc[i][j][2] + bv);
                o4.w = f2b(acc[i][j][3] + bv);
                *(ushort4*)(Cb + (long)cb * ldc + rb + l4 * 4) = o4;
            } else {
#pragma unroll
                for (int q = 0; q < 4; ++q) {
                    int r = rb + l4 * 4 + q;
                    float v = acc[i][j][q] + bv;
                    if (FLAGS & 4) v = fmaxf(v, 0.f);
                    if (FLAGS & 1) Cf[(long)r * ldc + cb] = v;
                    if (FLAGS & 2) Cb[(long)r * ldc + cb] = f2b(v);
                }
            }
        }
}

// ---------------- GCN aggregation ----------------
template <int ACT, int B16>
__global__ void k_gcn_agg(const float* __restrict__ msg, const int* __restrict__ sc,
                          const int* __restrict__ csc_row, const float* __restrict__ dinv,
                          const float* __restrict__ bias,
                          float* __restrict__ outf, ushort* __restrict__ outb) {
    int j = blockIdx.x;
    int d = threadIdx.x;
    float acc = 0.f;
    int a = sc[j], b = sc[j + 1];
    for (int i = a; i < b; ++i) {
        int r = csc_row[i];
        acc += dinv[r] * msg[(long)r * DM + d];
    }
    float dj = dinv[j];
    float v = dj * acc + dj * dj * msg[(long)j * DM + d] + bias[d];
    if (ACT) v = fmaxf(v, 0.f);
    if (B16) outb[(long)j * DM + d] = f2b(v);
    else outf[(long)j * DM + d] = v;
}

__global__ void k_concat(const ushort* __restrict__ nfb, const float* __restrict__ g,
                         ushort* __restrict__ xcb) {
    long i = (long)blockIdx.x * 256 + threadIdx.x;
    if (i >= (long)NN * 384) return;
    int r = (int)(i / 384), c = (int)(i % 384);
    xcb[i] = (c < DIN) ? nfb[(long)r * DIN + c] : f2b(g[(long)r * DM + (c - DIN)]);
}

// ---------------- barrier-free flash attention, SWAPPED operands ----------------
// grid: (NN/64, NH, NCH). 4 waves; wave w owns q-rows qb*64+w*16..+15.
// S^T = mfma(K, Q): lane q = l&15, kv = f*16 + (l>>4)*4 + reg -> softmax lane-local.
// PV: O^T = mfma(V^T, P^T). K/V/Q global access patterns identical to row-major loads.
__global__ __launch_bounds__(256, 4) void k_attn(
    const ushort* __restrict__ qkb, const ushort* __restrict__ vT,
    const float* __restrict__ ew, const float* __restrict__ eb,
    const int* __restrict__ bstart, const ushort* __restrict__ ents,
    float* __restrict__ opart, float2* __restrict__ ml) {
    __shared__ ushort Pl[4 * 16 * 64];  // 8 KB, per-wave 2KB: P^T [16 q][64 kv] XOR-swizzled
    const int qb = blockIdx.x, h = blockIdx.y, cz = blockIdx.z;
    const int tid = threadIdx.x, w = tid >> 6, l = tid & 63;
    const int l15 = l & 15, l4 = l >> 4;
    const float w0 = ew[h * 3 + 0], w1 = ew[h * 3 + 1], w2 = ew[h * 3 + 2] + eb[h];
    const float scale = 0.125f;
    bf16x8 qf[2];
    {
        const ushort* qp = qkb + (long)(qb * 64 + w * 16 + l15) * 512 + h * 64 + l4 * 8;
        qf[0] = *(const bf16x8*)(qp);
        qf[1] = *(const bf16x8*)(qp + 32);
    }
    const ushort* Kb = qkb + 256 + h * 64;          // row stride 512
    const ushort* Vb = vT + (long)(h * 64) * NN;    // row stride NN
    f32x4 o[4];
#pragma unroll
    for (int f = 0; f < 4; ++f) o[f] = (f32x4){0.f, 0.f, 0.f, 0.f};
    float m_run = -1e30f, l_run = 0.f;
    char* P = (char*)&Pl[w * 1024];
    const int bktbase = (qb * 4 + w) * 64;

    for (int t = cz * TPC; t < cz * TPC + TPC; ++t) {
        // ---- issue ALL K and V fragment loads for this tile up front ----
        bf16x8 kf[4][2], vf[4][2];
#pragma unroll
        for (int f = 0; f < 4; ++f) {
            const ushort* kp = Kb + (long)(t * 64 + f * 16 + l15) * 512 + l4 * 8;
            kf[f][0] = *(const bf16x8*)(kp);
            kf[f][1] = *(const bf16x8*)(kp + 32);
            const ushort* vp = Vb + (long)(f * 16 + l15) * NN + t * 64 + l4 * 8;
            vf[f][0] = *(const bf16x8*)(vp);
            vf[f][1] = *(const bf16x8*)(vp + 32);
        }
        // ---- S^T[kv][q] = scale * K Q^T ----
        f32x4 s4[4];
#pragma unroll
        for (int f = 0; f < 4; ++f) {
            f32x4 a = (f32x4){0.f, 0.f, 0.f, 0.f};
            a = __builtin_amdgcn_mfma_f32_16x16x32_bf16(kf[f][0], qf[0], a, 0, 0, 0);
            a = __builtin_amdgcn_mfma_f32_16x16x32_bf16(kf[f][1], qf[1], a, 0, 0, 0);
            s4[f] = a * scale;
        }
        // ---- sparse bias: lane q = l15; kv = f*16 + l4*4 + r ----
        {
            int bs = bstart[bktbase + t], be = bstart[bktbase + t + 1];
            for (int i = bs; i < be; ++i) {
                int rc = (int)ents[i];
                int r4 = rc >> 6, c6 = rc & 63;
                if (l15 == r4 && ((c6 >> 2) & 3) == l4) {
                    float arg = w0 * (float)(qb * 64 + w * 16 + r4) + w1 * (float)(t * 64 + c6) + w2;
                    float sig = 1.f / (1.f + __expf(-arg));
                    switch (((c6 >> 4) << 2) | (c6 & 3)) {
                        case 0:  s4[0][0] += sig; break; case 1:  s4[0][1] += sig; break;
                        case 2:  s4[0][2] += sig; break; case 3:  s4[0][3] += sig; break;
                        case 4:  s4[1][0] += sig; break; case 5:  s4[1][1] += sig; break;
                        case 6:  s4[1][2] += sig; break; case 7:  s4[1][3] += sig; break;
                        case 8:  s4[2][0] += sig; break; case 9:  s4[2][1] += sig; break;
                        case 10: s4[2][2] += sig; break; case 11: s4[2][3] += sig; break;
                        case 12: s4[3][0] += sig; break; case 13: s4[3][1] += sig; break;
                        case 14: s4[3][2] += sig; break; case 15: s4[3][3] += sig; break;
                    }
                }
            }
        }
        // ---- online softmax: per-lane row, 2 shuffles per reduction ----
        float me = s4[0][0];
#pragma unroll
        for (int f = 0; f < 4; ++f)
#pragma unroll
            for (int r = 0; r < 4; ++r) me = fmaxf(me, s4[f][r]);
        me = fmaxf(me, __shfl_xor(me, 16));
        me = fmaxf(me, __shfl_xor(me, 32));
        float mn = fmaxf(m_run, me);
        float fac = __expf(m_run - mn);
        m_run = mn;
        float rsum = 0.f;
#pragma unroll
        for (int f = 0; f < 4; ++f)
#pragma unroll
            for (int r = 0; r < 4; ++r) {
                float p = __expf(s4[f][r] - mn);
                s4[f][r] = p;
                rsum += p;
            }
        rsum += __shfl_xor(rsum, 16);
        rsum += __shfl_xor(rsum, 32);
        l_run = l_run * fac + rsum;
#pragma unroll
        for (int f = 0; f < 4; ++f)
#pragma unroll
            for (int r = 0; r < 4; ++r) o[f][r] *= fac;
        // ---- P^T -> per-wave LDS (bf16 pairs, slot-XOR swizzled) ----
#pragma unroll
        for (int f = 0; f < 4; ++f)
#pragma unroll
            for (int p = 0; p < 2; ++p) {
                uint u = cvt_pk_bf16(s4[f][2 * p], s4[f][2 * p + 1]);
                int slot = f * 2 + (l4 >> 1);
                int byte = l15 * 128 + ((slot ^ (l15 & 7)) << 4) + (l4 & 1) * 8 + p * 4;
                *(uint*)(P + byte) = u;
            }
        asm volatile("s_waitcnt lgkmcnt(0)" ::: "memory");
        __builtin_amdgcn_sched_barrier(0);
        // ---- O^T += V^T P^T ----
#pragma unroll
        for (int ks = 0; ks < 2; ++ks) {
            bf16x8 pb = *(const bf16x8*)(P + l15 * 128 + (((ks * 4 + l4) ^ (l15 & 7)) << 4));
#pragma unroll
            for (int fd = 0; fd < 4; ++fd)
                o[fd] = __builtin_amdgcn_mfma_f32_16x16x32_bf16(vf[fd][ks], pb, o[fd], 0, 0, 0);
        }
        __builtin_amdgcn_sched_barrier(0);
    }
    // ---- write partials: O^T lane q = l15, d = fd*16 + l4*4 + r ----
    long base = (((long)cz * NH + h) * NN + qb * 64 + w * 16 + l15) * 64;
#pragma unroll
    for (int fd = 0; fd < 4; ++fd)
#pragma unroll
        for (int r = 0; r < 4; ++r)
            opart[base + fd * 16 + l4 * 4 + r] = o[fd][r];
    if (l4 == 0)
        ml[((long)cz * NH + h) * NN + qb * 64 + w * 16 + l15] = make_float2(m_run, l_run);
}

// merge NCH chunk partials -> attnOb (bf16)
__global__ __launch_bounds__(256) void k_comb(const float* __restrict__ opart,
                                              const float2* __restrict__ ml,
                                              ushort* __restrict__ attnOb) {
    int t = blockIdx.x * 256 + threadIdx.x;  // NN*NH*64 total
    int d = t & 63;
    int r = (t >> 6) & (NN - 1);
    int h = t >> 18;
    float2 mls[NCH];
    float M = -1e30f;
#pragma unroll
    for (int c = 0; c < NCH; ++c) {
        mls[c] = ml[((long)c * NH + h) * NN + r];
        M = fmaxf(M, mls[c].x);
    }
    float s = 0.f, ov = 0.f;
#pragma unroll
    for (int c = 0; c < NCH; ++c) {
        float e = __expf(mls[c].x - M);
        s += mls[c].y * e;
        ov += opart[(((long)c * NH + h) * NN + r) * 64 + d] * e;
    }
    attnOb[(long)r * DM + h * 64 + d] = f2b(ov / s);
}

// ---------------- layernorm / output ----------------

__global__ __launch_bounds__(256) void k_add_ln(
    float* __restrict__ x, ushort* __restrict__ xb, const float* __restrict__ y,
    const float* __restrict__ g, const float* __restrict__ b) {
    int row = blockIdx.x * 4 + (threadIdx.x >> 6);
    int lane = threadIdx.x & 63;
    float v[4];
#pragma unroll
    for (int i = 0; i < 4; ++i)
        v[i] = x[(long)row * DM + lane + 64 * i] + y[(long)row * DM + lane + 64 * i];
    float s = v[0] + v[1] + v[2] + v[3];
#pragma unroll
    for (int o = 1; o < 64; o <<= 1) s += __shfl_xor(s, o);
    float m = s * (1.f / 256.f);
    float q = 0.f;
#pragma unroll
    for (int i = 0; i < 4; ++i) { float d = v[i] - m; q += d * d; }
#pragma unroll
    for (int o = 1; o < 64; o <<= 1) q += __shfl_xor(q, o);
    float rs = rsqrtf(q * (1.f / 256.f) + 1e-5f);
#pragma unroll
    for (int i = 0; i < 4; ++i) {
        int c = lane + 64 * i;
        float val = (v[i] - m) * rs * g[c] + b[c];
        x[(long)row * DM + c] = val;
        xb[(long)row * DM + c] = f2b(val);
    }
}

__global__ void k_out(const float* __restrict__ x, const float* __restrict__ w,
                      const float* __restrict__ b, float* __restrict__ out) {
    int row = blockIdx.x;
    int lane = threadIdx.x;
    float s = 0.f;
#pragma unroll
    for (int i = 0; i < 4; ++i) s += x[(long)row * DM + lane + 64 * i] * w[lane + 64 * i];
#pragma unroll
    for (int o = 1; o < 64; o <<= 1) s += __shfl_xor(s, o);
    if (lane == 0) out[row] = 1.f / (1.f + expf(-(s + b[0])));
}

__global__ void k_sentinel(float* out, int n) {
    int i = blockIdx.x * 256 + threadIdx.x;
    if (i < n) out[i] = 1.0e9f;
}

// ---------------- host ----------------

extern "C" void kernel_launch(void* const* d_in, const int* in_sizes, int n_in,
                              void* d_out, int out_size, void* d_ws, size_t ws_size,
                              hipStream_t stream) {
    const float* nf = (const float*)d_in[0];
    const int* ei = (const int*)d_in[1];
    const int* erow = ei;
    const int* ecol = ei + NE;
    const float* gcn1_w = (const float*)d_in[2];
    const float* gcn1_b = (const float*)d_in[3];
    const float* gcn2_w = (const float*)d_in[4];
    const float* gcn2_b = (const float*)d_in[5];
    const float* edge_w = (const float*)d_in[6];
    const float* edge_b = (const float*)d_in[7];
    const float* proj_w = (const float*)d_in[8];
    const float* proj_b = (const float*)d_in[9];
    const float* wqkv = (const float*)d_in[10];
    const float* bqkv = (const float*)d_in[11];
    const float* wo = (const float*)d_in[12];
    const float* bo = (const float*)d_in[13];
    const float* ffn_w1 = (const float*)d_in[14];
    const float* ffn_b1 = (const float*)d_in[15];
    const float* ffn_w2 = (const float*)d_in[16];
    const float* ffn_b2 = (const float*)d_in[17];
    const float* ln1_g = (const float*)d_in[18];
    const float* ln1_b = (const float*)d_in[19];
    const float* ln2_g = (const float*)d_in[20];
    const float* ln2_b = (const float*)d_in[21];
    const float* out_w = (const float*)d_in[22];
    const float* out_b = (const float*)d_in[23];
    float* out = (float*)d_out;

    char* wp = (char*)d_ws;
    size_t off = 0;
    auto alloc = [&](size_t bytes) -> void* {
        void* p = wp + off;
        off = (off + bytes + 255) & ~(size_t)255;
        return p;
    };
    // big union block (32 MB): msg (GCN) / opart (attn) / ffnHb+ybuf (ffn)
    char* big = (char*)alloc((size_t)NCH * NH * NN * 64 * 4);
    float* msg = (float*)big;
    float* opart = (float*)big;
    ushort* ffnHb = (ushort*)big;                           // 8 MB
    float* ybuf = (float*)(big + (size_t)8 * 1024 * 1024);  // 4 MB
    float* x = (float*)alloc((size_t)NN * DM * 4);
    ushort* xb = (ushort*)alloc((size_t)NN * DM * 2);
    ushort* xcb = (ushort*)alloc((size_t)NN * 384 * 2);
    ushort* hb = (ushort*)alloc((size_t)NN * DM * 2);
    float* g = (float*)alloc((size_t)NN * DM * 4);
    ushort* qkb = (ushort*)alloc((size_t)NN * 512 * 2);
    ushort* vT = (ushort*)alloc((size_t)DM * NN * 2);
    ushort* attnOb = (ushort*)alloc((size_t)NN * DM * 2);
    float2* ml = (float2*)alloc((size_t)NCH * NH * NN * 8);
    ushort* nfb = (ushort*)alloc((size_t)NN * DIN * 2);
    ushort* wqkvb = (ushort*)alloc((size_t)NL * 768 * DM * 2);
    ushort* wob = (ushort*)alloc((size_t)NL * DM * DM * 2);
    ushort* f1b = (ushort*)alloc((size_t)NL * 1024 * DM * 2);
    ushort* f2bw = (ushort*)alloc((size_t)NL * DM * 1024 * 2);
    ushort* g1b = (ushort*)alloc((size_t)DM * DIN * 2);
    ushort* g2b = (ushort*)alloc((size_t)DM * DM * 2);
    ushort* pjb = (ushort*)alloc((size_t)DM * 384 * 2);
    uint* bitmap = (uint*)alloc((size_t)NN * NN / 8);
    unsigned char* flag = (unsigned char*)alloc(NE);
    int* cnt_c = (int*)alloc((size_t)NN * 4);
    int* bcnt = (int*)alloc((size_t)NBKT * 4);
    int* sc = (int*)alloc((size_t)(NN + 1) * 4);
    int* bstart = (int*)alloc((size_t)(NBKT + 1) * 4);
    int* fc = (int*)alloc((size_t)NN * 4);
    int* bfill = (int*)alloc((size_t)NBKT * 4);
    int* csc_row = (int*)alloc((size_t)NE * 4);
    ushort* ents = (ushort*)alloc((size_t)NE * 2);
    float* dinv = (float*)alloc((size_t)NN * 4);

    if (off > ws_size) {
        k_sentinel<<<(out_size + 255) / 256, 256, 0, stream>>>(out, out_size);
        return;
    }

    // ---- preprocessing ----
    hipMemsetAsync(bitmap, 0, (size_t)NN * NN / 8, stream);
    hipMemsetAsync(cnt_c, 0, NN * 4, stream);
    hipMemsetAsync(bcnt, 0, NBKT * 4, stream);
    hipMemsetAsync(fc, 0, NN * 4, stream);
    hipMemsetAsync(bfill, 0, NBKT * 4, stream);
    k_edge1<<<NE / 256, 256, 0, stream>>>(erow, ecol, bitmap, cnt_c, bcnt, flag);
    k_scan<NN><<<1, 256, 0, stream>>>(cnt_c, sc);
    k_scan<NBKT><<<1, 256, 0, stream>>>(bcnt, bstart);
    k_edge2<<<NE / 256, 256, 0, stream>>>(erow, ecol, flag, sc, fc, csc_row, bstart, bfill, ents);
    k_dinv<<<NN / 256, 256, 0, stream>>>(cnt_c, dinv);

    // ---- weight/input conversion ----
    CvtP cp;
    cp.s[0] = nf;      cp.d[0] = nfb;   cp.n[0] = NN * DIN;
    cp.s[1] = wqkv;    cp.d[1] = wqkvb; cp.n[1] = NL * 768 * DM;
    cp.s[2] = wo;      cp.d[2] = wob;   cp.n[2] = NL * DM * DM;
    cp.s[3] = ffn_w1;  cp.d[3] = f1b;   cp.n[3] = NL * 1024 * DM;
    cp.s[4] = ffn_w2;  cp.d[4] = f2bw;  cp.n[4] = NL * DM * 1024;
    cp.s[5] = gcn1_w;  cp.d[5] = g1b;   cp.n[5] = DM * DIN;
    cp.s[6] = gcn2_w;  cp.d[6] = g2b;   cp.n[6] = DM * DM;
    cp.s[7] = proj_w;  cp.d[7] = pjb;   cp.n[7] = DM * 384;
    k_cvt<<<dim3(768, 8), 256, 0, stream>>>(cp);

    // ---- GCN ----
    k_gemm_b<1><<<dim3(DM / 128, NN / 128), 256, 0, stream>>>(
        nfb, DIN, g1b, DIN, msg, nullptr, DM, DIN, nullptr);
    k_gcn_agg<1, 1><<<NN, DM, 0, stream>>>(msg, sc, csc_row, dinv, gcn1_b, nullptr, hb);
    k_gemm_b<1><<<dim3(DM / 128, NN / 128), 256, 0, stream>>>(
        hb, DM, g2b, DM, msg, nullptr, DM, DM, nullptr);
    k_gcn_agg<0, 0><<<NN, DM, 0, stream>>>(msg, sc, csc_row, dinv, gcn2_b, g, nullptr);
    // ---- proj ----
    k_concat<<<(NN * 384 + 255) / 256, 256, 0, stream>>>(nfb, g, xcb);
    k_gemm_b<3><<<dim3(DM / 128, NN / 128), 256, 0, stream>>>(
        xcb, 384, pjb, 384, x, xb, DM, 384, proj_b);

    for (int l = 0; l < NL; ++l) {
        // q,k -> qkb [n][512]; v -> vT [256][NN] transposed
        k_gemm_b<2><<<dim3(512 / 128, NN / 128), 256, 0, stream>>>(
            xb, DM, wqkvb + (long)l * 768 * DM, DM, nullptr, qkb, 512, DM,
            bqkv + (long)l * 768);
        k_gemm_b<8><<<dim3(DM / 128, NN / 128), 256, 0, stream>>>(
            xb, DM, wqkvb + (long)l * 768 * DM + 512 * DM, DM, nullptr, vT, NN, DM,
            bqkv + (long)l * 768 + 512);
        k_attn<<<dim3(NN / 64, NH, NCH), 256, 0, stream>>>(
            qkb, vT, edge_w, edge_b, bstart, ents, opart, ml);
        k_comb<<<NN * NH * 64 / 256, 256, 0, stream>>>(opart, ml, attnOb);
        k_gemm_b<1><<<dim3(DM / 128, NN / 128), 256, 0, stream>>>(
            attnOb, DM, wob + (long)l * DM * DM, DM, ybuf, nullptr, DM, DM,
            bo + (long)l * DM);
        k_add_ln<<<NN / 4, 256, 0, stream>>>(x, xb, ybuf, ln1_g + (long)l * DM, ln1_b + (long)l * DM);
        k_gemm_b<6><<<dim3(1024 / 128, NN / 128), 256, 0, stream>>>(
            xb, DM, f1b + (long)l * 1024 * DM, DM, nullptr, ffnHb, 1024, DM,
            ffn_b1 + (long)l * 1024);
        k_gemm_b<1><<<dim3(DM / 128, NN / 128), 256, 0, stream>>>(
            ffnHb, 1024, f2bw + (long)l * DM * 1024, 1024, ybuf, nullptr, DM, 1024,
            ffn_b2 + (long)l * DM);
        k_add_ln<<<NN / 4, 256, 0, stream>>>(x, xb, ybuf, ln2_g + (long)l * DM, ln2_b + (long)l * DM);
    }
    k_out<<<NN, 64, 0, stream>>>(x, out_w, out_b, out);
}